// Round 3
// baseline (1688.157 us; speedup 1.0000x reference)
//
#include <hip/hip_runtime.h>
#include <hip/hip_bf16.h>
#include <math.h>

// Problem constants
#define EMBED 512
#define NHEAD 8
#define HDIM 64
#define FFN 2048
#define BB 4
#define SS 2048
#define MROWS (BB*SS)   // 8192
#define LN_EPS 1e-5f

typedef __attribute__((ext_vector_type(8))) short short8;
typedef __attribute__((ext_vector_type(4))) float floatx4;

__device__ inline float bf2f(__hip_bfloat16 x) { return __bfloat162float(x); }
__device__ inline __hip_bfloat16 f2bf(float x) { return __float2bfloat16(x); }

__device__ inline float gelu_f(float x) {
    return 0.5f * x * (1.0f + erff(x * 0.70710678118654752f));
}

// ---------------- runtime dtype detection ----------------
// If inputs are fp32, samples read as float are ~N(0,1). If inputs are bf16,
// a bf16-pair reinterpreted as fp32 has exponent bits taken from the high
// bf16's exponent<<1 -> |v| ~ 1e34+/inf almost surely. flag=1 means fp32.
__global__ void detect_kernel(const void* __restrict__ q, int* __restrict__ flag) {
    const float* qf = (const float*)q;
    int lane = threadIdx.x;          // 64 threads
    float v = qf[lane * 1024 + 7];   // max idx 64519 << 1M floats, in bounds either dtype
    bool ok = (v == v) && (fabsf(v) > 0x1p-40f) && (fabsf(v) < 0x1p40f);
    unsigned long long m = __ballot(ok);
    if (lane == 0) *flag = (__popcll(m) >= 32) ? 1 : 0;
}

// ---------------- weight transpose+convert: src[R][C] -> dst[C][R] (bf16), C = 1<<logC ----------------
__global__ __launch_bounds__(256) void transpose_cvt_kernel(
    const void* __restrict__ src, __hip_bfloat16* __restrict__ dst,
    int R, int logC, const int* __restrict__ dflag)
{
    const int f32 = *dflag;
    int i = blockIdx.x * 256 + threadIdx.x;
    int C = 1 << logC;
    if (i < (R << logC)) {
        int r = i >> logC, c = i & (C - 1);
        __hip_bfloat16 v = f32 ? f2bf(((const float*)src)[i])
                               : ((const __hip_bfloat16*)src)[i];
        dst[(size_t)c * R + r] = v;
    }
}

// ---------------- GEMM: C[M][N] = act(A[M][K] @ Bt[N][K]^T + bias) ----------------
// 128x128 block tile, 4 waves (2x2), each wave 64x64 via 4x4 MFMA 16x16x32 bf16 tiles.
// A may be external (dtype per dflag) or internal bf16 (a_ext=0). bias is always external.
template<int ACT>  // 0 = none, 1 = exact gelu
__global__ __launch_bounds__(256) void gemm_bt_kernel(
    const void* __restrict__ Ax,
    const __hip_bfloat16* __restrict__ Bt,
    const void* __restrict__ bias,
    __hip_bfloat16* __restrict__ C,
    int M, int N, int K, int a_ext, const int* __restrict__ dflag)
{
    const int f32 = *dflag;
    const bool a32 = (a_ext != 0) && (f32 != 0);
    const __hip_bfloat16* Ab = (const __hip_bfloat16*)Ax;
    const float* Af = (const float*)Ax;

    const int bm = blockIdx.x * 128;
    const int bn = blockIdx.y * 128;
    const int t = threadIdx.x;
    const int wave = t >> 6, lane = t & 63;
    const int wm = (wave >> 1) * 64, wn = (wave & 1) * 64;
    const int quad = lane >> 4, r = lane & 15;

    // alignas(16): uint4/short8 LDS accesses require 16B base; row stride 40*2=80B is 16B-multiple
    __shared__ alignas(16) __hip_bfloat16 As[128][40];
    __shared__ alignas(16) __hip_bfloat16 Bs[128][40];

    floatx4 acc[4][4];
    #pragma unroll
    for (int i = 0; i < 4; ++i)
        #pragma unroll
        for (int j = 0; j < 4; ++j)
            acc[i][j] = (floatx4){0.f, 0.f, 0.f, 0.f};

    const int srow = t >> 2;         // t/4
    const int scol = (t & 3) * 8;    // (t%4)*8

    for (int kt = 0; kt < K; kt += 32) {
        #pragma unroll
        for (int it = 0; it < 2; ++it) {
            int row = srow + it * 64;
            if (a32) {
                const float* src = Af + (size_t)(bm + row) * K + kt + scol;
                float4 f0 = *reinterpret_cast<const float4*>(src);
                float4 f1 = *reinterpret_cast<const float4*>(src + 4);
                alignas(16) __hip_bfloat16 h[8] = {
                    f2bf(f0.x), f2bf(f0.y), f2bf(f0.z), f2bf(f0.w),
                    f2bf(f1.x), f2bf(f1.y), f2bf(f1.z), f2bf(f1.w)};
                *reinterpret_cast<uint4*>(&As[row][scol]) = *reinterpret_cast<const uint4*>(h);
            } else {
                uint4 av = *reinterpret_cast<const uint4*>(Ab + (size_t)(bm + row) * K + kt + scol);
                *reinterpret_cast<uint4*>(&As[row][scol]) = av;
            }
            uint4 bv = *reinterpret_cast<const uint4*>(Bt + (size_t)(bn + row) * K + kt + scol);
            *reinterpret_cast<uint4*>(&Bs[row][scol]) = bv;
        }
        __syncthreads();
        short8 af[4], bfr[4];
        #pragma unroll
        for (int i = 0; i < 4; ++i)
            af[i] = *reinterpret_cast<const short8*>(&As[wm + i * 16 + r][quad * 8]);
        #pragma unroll
        for (int j = 0; j < 4; ++j)
            bfr[j] = *reinterpret_cast<const short8*>(&Bs[wn + j * 16 + r][quad * 8]);
        #pragma unroll
        for (int i = 0; i < 4; ++i)
            #pragma unroll
            for (int j = 0; j < 4; ++j)
                acc[i][j] = __builtin_amdgcn_mfma_f32_16x16x32_bf16(af[i], bfr[j], acc[i][j], 0, 0, 0);
        __syncthreads();
    }

    #pragma unroll
    for (int j = 0; j < 4; ++j) {
        const int n = bn + wn + j * 16 + r;
        const float bvv = f32 ? ((const float*)bias)[n]
                              : bf2f(((const __hip_bfloat16*)bias)[n]);
        #pragma unroll
        for (int i = 0; i < 4; ++i) {
            #pragma unroll
            for (int v = 0; v < 4; ++v) {
                int m = bm + wm + i * 16 + quad * 4 + v;
                float x = acc[i][j][v] + bvv;
                if (ACT == 1) x = gelu_f(x);
                C[(size_t)m * N + n] = f2bf(x);
            }
        }
    }
}

// ---------------- flash attention (vector ALU), 16 queries per block ----------------
// grid: (S/16, B*H), block 256. Wave qg owns query rows {qg, qg+4, qg+8, qg+12}.
// All operands internal bf16.
__global__ __launch_bounds__(256) void attn_kernel(
    const __hip_bfloat16* __restrict__ Qg,
    const __hip_bfloat16* __restrict__ Kg,
    const __hip_bfloat16* __restrict__ Vg,
    __hip_bfloat16* __restrict__ ctx)
{
    const int bh = blockIdx.y;
    const int b = bh >> 3, h = bh & 7;
    const int q0 = blockIdx.x * 16;
    const int t = threadIdx.x;
    const int lane = t & 63, qg = t >> 6;

    __shared__ alignas(16) float Qs[16][64];   // float4 reads; row 256B
    __shared__ alignas(16) float KsT[64][65];  // scalar access only; 65 pad -> conflict-free
    __shared__ alignas(16) float Vs[64][64];   // scalar access only
    __shared__ alignas(16) float Ps[16][64];   // float4 reads; row 256B

    const size_t head_off = (size_t)h * HDIM;
    const size_t bbase = (size_t)b * SS * EMBED;

    for (int i = t; i < 16 * 64; i += 256) {
        int qq = i >> 6, d = i & 63;
        Qs[qq][d] = bf2f(Qg[bbase + (size_t)(q0 + qq) * EMBED + head_off + d]) * 0.125f;
    }

    float m_run[4] = {-1e30f, -1e30f, -1e30f, -1e30f};
    float l_run[4] = {0.f, 0.f, 0.f, 0.f};
    float o_acc[4] = {0.f, 0.f, 0.f, 0.f};

    for (int kt = 0; kt < SS; kt += 64) {
        __syncthreads();  // protect K/V tiles from previous iteration readers (also orders Qs)
        for (int i = t; i < 2048; i += 256) {
            int kk = i >> 5, d2 = (i & 31) * 2;
            size_t goff = bbase + (size_t)(kt + kk) * EMBED + head_off + d2;
            __hip_bfloat162 kp = *reinterpret_cast<const __hip_bfloat162*>(Kg + goff);
            __hip_bfloat162 vp = *reinterpret_cast<const __hip_bfloat162*>(Vg + goff);
            KsT[d2][kk] = __low2float(kp);
            KsT[d2 + 1][kk] = __high2float(kp);
            Vs[kk][d2] = __low2float(vp);
            Vs[kk][d2 + 1] = __high2float(vp);
        }
        __syncthreads();

        // scores: lane = key index
        float s[4] = {0.f, 0.f, 0.f, 0.f};
        for (int d = 0; d < 64; d += 4) {
            float k0 = KsT[d][lane], k1 = KsT[d + 1][lane];
            float k2 = KsT[d + 2][lane], k3 = KsT[d + 3][lane];
            #pragma unroll
            for (int j = 0; j < 4; ++j) {
                float4 q4 = *reinterpret_cast<const float4*>(&Qs[qg + 4 * j][d]);
                s[j] += q4.x * k0 + q4.y * k1 + q4.z * k2 + q4.w * k3;
            }
        }

        // online softmax per row (wave-wide)
        float scalev[4];
        #pragma unroll
        for (int j = 0; j < 4; ++j) {
            float mt = s[j];
            #pragma unroll
            for (int off = 32; off; off >>= 1) mt = fmaxf(mt, __shfl_xor(mt, off, 64));
            float mn = fmaxf(m_run[j], mt);
            float p = __expf(s[j] - mn);
            float ps = p;
            #pragma unroll
            for (int off = 32; off; off >>= 1) ps += __shfl_xor(ps, off, 64);
            scalev[j] = __expf(m_run[j] - mn);
            l_run[j] = l_run[j] * scalev[j] + ps;
            m_run[j] = mn;
            Ps[qg + 4 * j][lane] = p;   // same-wave LDS RAW: compiler orders via lgkmcnt
        }

        // PV accumulate: lane = dim index
        #pragma unroll
        for (int j = 0; j < 4; ++j) o_acc[j] *= scalev[j];
        for (int k2 = 0; k2 < 64; k2 += 4) {
            float v0 = Vs[k2][lane], v1 = Vs[k2 + 1][lane];
            float v2 = Vs[k2 + 2][lane], v3 = Vs[k2 + 3][lane];
            #pragma unroll
            for (int j = 0; j < 4; ++j) {
                float4 p4 = *reinterpret_cast<const float4*>(&Ps[qg + 4 * j][k2]);
                o_acc[j] += p4.x * v0 + p4.y * v1 + p4.z * v2 + p4.w * v3;
            }
        }
    }

    #pragma unroll
    for (int j = 0; j < 4; ++j) {
        float o = o_acc[j] / l_run[j];
        ctx[bbase + (size_t)(q0 + qg + 4 * j) * EMBED + head_off + lane] = f2bf(o);
    }
}

// ---------------- fused residual-add + LayerNorm ----------------
__device__ inline float block_reduce_sum(float v, float* sbuf) {
    #pragma unroll
    for (int off = 32; off; off >>= 1) v += __shfl_xor(v, off, 64);
    int wave = threadIdx.x >> 6;
    if ((threadIdx.x & 63) == 0) sbuf[wave] = v;
    __syncthreads();
    float r = sbuf[0] + sbuf[1] + sbuf[2] + sbuf[3];
    __syncthreads();
    return r;
}

// X: residual input (external if x_ext). Y: internal bf16. g/bt: external.
// out: d_out (external dtype) if out_ext else internal bf16.
__global__ __launch_bounds__(256) void add_ln_kernel(
    const void* __restrict__ X,
    const __hip_bfloat16* __restrict__ Y,
    const void* __restrict__ g,
    const void* __restrict__ bt,
    void* __restrict__ out,
    int x_ext, int out_ext, const int* __restrict__ dflag)
{
    __shared__ float sbuf[4];
    const int f32 = *dflag;
    const bool x32 = (x_ext != 0) && (f32 != 0);
    const bool o32 = (out_ext != 0) && (f32 != 0);
    const int row = blockIdx.x;
    const size_t base = (size_t)row * EMBED;
    const int t = threadIdx.x;

    float xa = x32 ? ((const float*)X)[base + t]
                   : bf2f(((const __hip_bfloat16*)X)[base + t]);
    float xb = x32 ? ((const float*)X)[base + t + 256]
                   : bf2f(((const __hip_bfloat16*)X)[base + t + 256]);
    float x0 = xa + bf2f(Y[base + t]);
    float x1 = xb + bf2f(Y[base + t + 256]);
    float s = block_reduce_sum(x0 + x1, sbuf);
    float mu = s * (1.0f / EMBED);
    float d0 = x0 - mu, d1 = x1 - mu;
    float vs = block_reduce_sum(d0 * d0 + d1 * d1, sbuf);
    float rstd = rsqrtf(vs * (1.0f / EMBED) + LN_EPS);

    float g0 = f32 ? ((const float*)g)[t]        : bf2f(((const __hip_bfloat16*)g)[t]);
    float g1v = f32 ? ((const float*)g)[t + 256] : bf2f(((const __hip_bfloat16*)g)[t + 256]);
    float b0 = f32 ? ((const float*)bt)[t]        : bf2f(((const __hip_bfloat16*)bt)[t]);
    float b1v = f32 ? ((const float*)bt)[t + 256] : bf2f(((const __hip_bfloat16*)bt)[t + 256]);

    float o0 = d0 * rstd * g0 + b0;
    float o1 = d1 * rstd * g1v + b1v;
    if (o32) {
        ((float*)out)[base + t] = o0;
        ((float*)out)[base + t + 256] = o1;
    } else {
        ((__hip_bfloat16*)out)[base + t] = f2bf(o0);
        ((__hip_bfloat16*)out)[base + t + 256] = f2bf(o1);
    }
}

// ---------------- launch ----------------
extern "C" void kernel_launch(void* const* d_in, const int* in_sizes, int n_in,
                              void* d_out, int out_size, void* d_ws, size_t ws_size,
                              hipStream_t stream)
{
    (void)in_sizes; (void)n_in; (void)out_size; (void)ws_size;

    const void* query = d_in[0];
    const void* keyi  = d_in[1];
    const void* vali  = d_in[2];
    const void* Wq = d_in[3];  const void* bq = d_in[4];
    const void* Wk = d_in[5];  const void* bk = d_in[6];
    const void* Wv = d_in[7];  const void* bv = d_in[8];
    const void* Wo = d_in[9];  const void* bo = d_in[10];
    const void* g1 = d_in[11]; const void* be1 = d_in[12];
    const void* g2 = d_in[13]; const void* be2 = d_in[14];
    const void* W1 = d_in[15]; const void* b1 = d_in[16];
    const void* W2 = d_in[17]; const void* b2 = d_in[18];

    // ---- workspace: [flag][weightsT][6 x 4M bf16 bufs]; peak ~= 54 MB ----
    int* dflag = (int*)d_ws;
    __hip_bfloat16* p = (__hip_bfloat16*)((char*)d_ws + 64);
    __hip_bfloat16* WqT = p;
    __hip_bfloat16* WkT = WqT + 512 * 512;
    __hip_bfloat16* WvT = WkT + 512 * 512;
    __hip_bfloat16* WoT = WvT + 512 * 512;
    __hip_bfloat16* W1T = WoT + 512 * 512;       // [FFN][EMBED], 1M elems
    __hip_bfloat16* W2T = W1T + 512 * 2048;      // [EMBED][FFN], 1M elems
    __hip_bfloat16* buf = W2T + 512 * 2048;
    const size_t NB = (size_t)MROWS * EMBED;     // 4M elems
    __hip_bfloat16* Qb  = buf;                   // buf0
    __hip_bfloat16* Kb  = buf + NB;              // buf1
    __hip_bfloat16* Vb  = buf + 2 * NB;          // buf2
    __hip_bfloat16* ctx = buf + 3 * NB;          // buf3
    // aliases (lifetimes disjoint):
    __hip_bfloat16* prj = Qb;                    // live after attn (Qb dead)
    __hip_bfloat16* x1  = Kb;                    // live after prj consumed (Kb dead)
    __hip_bfloat16* hbf = Vb;                    // 16M elems: buf2..buf5 (Vb,ctx dead by FFN1)

    // dtype probe (must run every call: ws is re-poisoned before each launch)
    detect_kernel<<<1, 64, 0, stream>>>(query, dflag);

    // weight transposes (+convert to bf16)
    transpose_cvt_kernel<<<512 * 512 / 256, 256, 0, stream>>>(Wq, WqT, 512, 9, dflag);
    transpose_cvt_kernel<<<512 * 512 / 256, 256, 0, stream>>>(Wk, WkT, 512, 9, dflag);
    transpose_cvt_kernel<<<512 * 512 / 256, 256, 0, stream>>>(Wv, WvT, 512, 9, dflag);
    transpose_cvt_kernel<<<512 * 512 / 256, 256, 0, stream>>>(Wo, WoT, 512, 9, dflag);
    transpose_cvt_kernel<<<512 * 2048 / 256, 256, 0, stream>>>(W1, W1T, 512, 11, dflag);  // [512][2048] -> [2048][512]
    transpose_cvt_kernel<<<512 * 2048 / 256, 256, 0, stream>>>(W2, W2T, 2048, 9, dflag);  // [2048][512] -> [512][2048]

    // QKV projections (A = external input)
    gemm_bt_kernel<0><<<dim3(MROWS / 128, EMBED / 128), 256, 0, stream>>>(query, WqT, bq, Qb, MROWS, EMBED, EMBED, 1, dflag);
    gemm_bt_kernel<0><<<dim3(MROWS / 128, EMBED / 128), 256, 0, stream>>>(keyi,  WkT, bk, Kb, MROWS, EMBED, EMBED, 1, dflag);
    gemm_bt_kernel<0><<<dim3(MROWS / 128, EMBED / 128), 256, 0, stream>>>(vali,  WvT, bv, Vb, MROWS, EMBED, EMBED, 1, dflag);

    // attention
    attn_kernel<<<dim3(SS / 16, BB * NHEAD), 256, 0, stream>>>(Qb, Kb, Vb, ctx);

    // output projection + LN1 (residual = external query)
    gemm_bt_kernel<0><<<dim3(MROWS / 128, EMBED / 128), 256, 0, stream>>>(ctx, WoT, bo, prj, MROWS, EMBED, EMBED, 0, dflag);
    add_ln_kernel<<<MROWS, 256, 0, stream>>>(query, prj, g1, be1, x1, 1, 0, dflag);

    // FFN
    gemm_bt_kernel<1><<<dim3(MROWS / 128, FFN / 128), 256, 0, stream>>>(x1, W1T, b1, hbf, MROWS, FFN, EMBED, 0, dflag);
    gemm_bt_kernel<0><<<dim3(MROWS / 128, EMBED / 128), 256, 0, stream>>>(hbf, W2T, b2, prj, MROWS, EMBED, FFN, 0, dflag);
    add_ln_kernel<<<MROWS, 256, 0, stream>>>(x1, prj, g2, be2, d_out, 0, 1, dflag);
}

// Round 4
// 530.616 us; speedup vs baseline: 3.1815x; 3.1815x over previous
//
#include <hip/hip_runtime.h>
#include <hip/hip_bf16.h>
#include <math.h>

// Problem constants
#define EMBED 512
#define NHEAD 8
#define HDIM 64
#define FFN 2048
#define BB 4
#define SS 2048
#define MROWS (BB*SS)   // 8192
#define LN_EPS 1e-5f

typedef __attribute__((ext_vector_type(8))) short short8;
typedef __attribute__((ext_vector_type(4))) float floatx4;

__device__ inline float bf2f(__hip_bfloat16 x) { return __bfloat162float(x); }
__device__ inline __hip_bfloat16 f2bf(float x) { return __float2bfloat16(x); }

__device__ inline float gelu_f(float x) {
    return 0.5f * x * (1.0f + erff(x * 0.70710678118654752f));
}

// ---------------- runtime dtype detection ----------------
__global__ void detect_kernel(const void* __restrict__ q, int* __restrict__ flag) {
    const float* qf = (const float*)q;
    int lane = threadIdx.x;          // 64 threads
    float v = qf[lane * 1024 + 7];
    bool ok = (v == v) && (fabsf(v) > 0x1p-40f) && (fabsf(v) < 0x1p40f);
    unsigned long long m = __ballot(ok);
    if (lane == 0) *flag = (__popcll(m) >= 32) ? 1 : 0;
}

// ---------------- weight transpose+convert: src[R][C] -> dst[C][R] (bf16) ----------------
__global__ __launch_bounds__(256) void transpose_cvt_kernel(
    const void* __restrict__ src, __hip_bfloat16* __restrict__ dst,
    int R, int logC, const int* __restrict__ dflag)
{
    const int f32 = *dflag;
    int i = blockIdx.x * 256 + threadIdx.x;
    int C = 1 << logC;
    if (i < (R << logC)) {
        int r = i >> logC, c = i & (C - 1);
        __hip_bfloat16 v = f32 ? f2bf(((const float*)src)[i])
                               : ((const __hip_bfloat16*)src)[i];
        dst[(size_t)c * R + r] = v;
    }
}

// ---------------- GEMM: C[M][N] = act(A[M][K] @ Bt[N][K]^T + bias) ----------------
// 128x128 tile, 4 waves (2x2), 4x4 MFMA 16x16x32 bf16 per wave.
// OUTT=1: write output as Vt[((b*8+h)*64+d)*2048 + s]  (head-transposed V for attention)
template<int ACT, int OUTT>
__global__ __launch_bounds__(256) void gemm_bt_kernel(
    const void* __restrict__ Ax,
    const __hip_bfloat16* __restrict__ Bt,
    const void* __restrict__ bias,
    __hip_bfloat16* __restrict__ C,
    int M, int N, int K, int a_ext, const int* __restrict__ dflag)
{
    const int f32 = *dflag;
    const bool a32 = (a_ext != 0) && (f32 != 0);
    const __hip_bfloat16* Ab = (const __hip_bfloat16*)Ax;
    const float* Af = (const float*)Ax;

    const int bm = blockIdx.x * 128;
    const int bn = blockIdx.y * 128;
    const int t = threadIdx.x;
    const int wave = t >> 6, lane = t & 63;
    const int wm = (wave >> 1) * 64, wn = (wave & 1) * 64;
    const int quad = lane >> 4, r = lane & 15;

    __shared__ alignas(16) __hip_bfloat16 As[128][40];
    __shared__ alignas(16) __hip_bfloat16 Bs[128][40];

    floatx4 acc[4][4];
    #pragma unroll
    for (int i = 0; i < 4; ++i)
        #pragma unroll
        for (int j = 0; j < 4; ++j)
            acc[i][j] = (floatx4){0.f, 0.f, 0.f, 0.f};

    const int srow = t >> 2;
    const int scol = (t & 3) * 8;

    for (int kt = 0; kt < K; kt += 32) {
        #pragma unroll
        for (int it = 0; it < 2; ++it) {
            int row = srow + it * 64;
            if (a32) {
                const float* src = Af + (size_t)(bm + row) * K + kt + scol;
                float4 f0 = *reinterpret_cast<const float4*>(src);
                float4 f1 = *reinterpret_cast<const float4*>(src + 4);
                alignas(16) __hip_bfloat16 h[8] = {
                    f2bf(f0.x), f2bf(f0.y), f2bf(f0.z), f2bf(f0.w),
                    f2bf(f1.x), f2bf(f1.y), f2bf(f1.z), f2bf(f1.w)};
                *reinterpret_cast<uint4*>(&As[row][scol]) = *reinterpret_cast<const uint4*>(h);
            } else {
                uint4 av = *reinterpret_cast<const uint4*>(Ab + (size_t)(bm + row) * K + kt + scol);
                *reinterpret_cast<uint4*>(&As[row][scol]) = av;
            }
            uint4 bv = *reinterpret_cast<const uint4*>(Bt + (size_t)(bn + row) * K + kt + scol);
            *reinterpret_cast<uint4*>(&Bs[row][scol]) = bv;
        }
        __syncthreads();
        short8 af[4], bfr[4];
        #pragma unroll
        for (int i = 0; i < 4; ++i)
            af[i] = *reinterpret_cast<const short8*>(&As[wm + i * 16 + r][quad * 8]);
        #pragma unroll
        for (int j = 0; j < 4; ++j)
            bfr[j] = *reinterpret_cast<const short8*>(&Bs[wn + j * 16 + r][quad * 8]);
        #pragma unroll
        for (int i = 0; i < 4; ++i)
            #pragma unroll
            for (int j = 0; j < 4; ++j)
                acc[i][j] = __builtin_amdgcn_mfma_f32_16x16x32_bf16(af[i], bfr[j], acc[i][j], 0, 0, 0);
        __syncthreads();
    }

    #pragma unroll
    for (int j = 0; j < 4; ++j) {
        const int n = bn + wn + j * 16 + r;
        const float bvv = f32 ? ((const float*)bias)[n]
                              : bf2f(((const __hip_bfloat16*)bias)[n]);
        #pragma unroll
        for (int i = 0; i < 4; ++i) {
            #pragma unroll
            for (int v = 0; v < 4; ++v) {
                int m = bm + wm + i * 16 + quad * 4 + v;
                float x = acc[i][j][v] + bvv;
                if (ACT == 1) x = gelu_f(x);
                if (OUTT == 1) {
                    // m = b*2048+s ; n = h*64+d  ->  Vt[((b*8+h)*64+d)*2048 + s]
                    int bq = m >> 11, sq = m & 2047, hh = n >> 6, dd = n & 63;
                    C[((((size_t)bq << 3) + hh) * 64 + dd) * 2048 + sq] = f2bf(x);
                } else {
                    C[(size_t)m * N + n] = f2bf(x);
                }
            }
        }
    }
}

// ---------------- MFMA flash attention ----------------
// grid (S/64, B*H), block 256. Wave w owns 16 queries; 64-key tiles.
// Vt is head-transposed: [B*H][64 d][2048 s].
__global__ __launch_bounds__(256) void attn_mfma_kernel(
    const __hip_bfloat16* __restrict__ Qg,
    const __hip_bfloat16* __restrict__ Kg,
    const __hip_bfloat16* __restrict__ Vt,
    __hip_bfloat16* __restrict__ ctx)
{
    const int bh = blockIdx.y;
    const int b = bh >> 3, h = bh & 7;
    const int q0 = blockIdx.x * 64;
    const int t = threadIdx.x;
    const int w = t >> 6, lane = t & 63;
    const int quad = lane >> 4, r = lane & 15;

    // 72 bf16 rows = 144 B = 36 dwords (== 4 mod 32 -> worst 2-way, free)
    __shared__ alignas(16) __hip_bfloat16 Ks[64][72];
    __shared__ alignas(16) __hip_bfloat16 VsT[64][72];   // [d][key]
    __shared__ alignas(16) __hip_bfloat16 Ps[4][16][72]; // per-wave P

    const size_t bbase = (size_t)b * SS * EMBED;
    const size_t hoff = (size_t)h * HDIM;
    const size_t vtbase = (size_t)bh * HDIM * SS;

    // Q A-fragments (loop-invariant): A[m=r][k=quad*8+j]
    short8 aq[2];
    {
        const __hip_bfloat16* qrow = Qg + bbase + (size_t)(q0 + w * 16 + r) * EMBED + hoff;
        aq[0] = *reinterpret_cast<const short8*>(qrow + quad * 8);
        aq[1] = *reinterpret_cast<const short8*>(qrow + 32 + quad * 8);
    }

    float m_run[4] = {-1e30f, -1e30f, -1e30f, -1e30f};
    float l_run[4] = {0.f, 0.f, 0.f, 0.f};
    floatx4 o_acc[4];
    #pragma unroll
    for (int nt = 0; nt < 4; ++nt) o_acc[nt] = (floatx4){0.f, 0.f, 0.f, 0.f};

    for (int kt = 0; kt < SS; kt += 64) {
        __syncthreads();  // all waves done reading prev K/V tiles
        #pragma unroll
        for (int c = t; c < 512; c += 256) {
            int row = c >> 3, col = (c & 7) * 8;
            *reinterpret_cast<uint4*>(&Ks[row][col]) =
                *reinterpret_cast<const uint4*>(Kg + bbase + (size_t)(kt + row) * EMBED + hoff + col);
            *reinterpret_cast<uint4*>(&VsT[row][col]) =
                *reinterpret_cast<const uint4*>(Vt + vtbase + (size_t)row * SS + kt + col);
        }
        __syncthreads();

        // QK^T: S[16q][64k] as 4 n-tiles
        floatx4 sc[4];
        #pragma unroll
        for (int nt = 0; nt < 4; ++nt) sc[nt] = (floatx4){0.f, 0.f, 0.f, 0.f};
        #pragma unroll
        for (int nt = 0; nt < 4; ++nt) {
            short8 bk0 = *reinterpret_cast<const short8*>(&Ks[nt * 16 + r][quad * 8]);
            short8 bk1 = *reinterpret_cast<const short8*>(&Ks[nt * 16 + r][32 + quad * 8]);
            sc[nt] = __builtin_amdgcn_mfma_f32_16x16x32_bf16(aq[0], bk0, sc[nt], 0, 0, 0);
            sc[nt] = __builtin_amdgcn_mfma_f32_16x16x32_bf16(aq[1], bk1, sc[nt], 0, 0, 0);
        }

        // online softmax; row = quad*4+v, col = nt*16+r
        #pragma unroll
        for (int v = 0; v < 4; ++v) {
            float s0 = sc[0][v] * 0.125f, s1 = sc[1][v] * 0.125f;
            float s2 = sc[2][v] * 0.125f, s3 = sc[3][v] * 0.125f;
            float mt = fmaxf(fmaxf(s0, s1), fmaxf(s2, s3));
            mt = fmaxf(mt, __shfl_xor(mt, 1, 64));
            mt = fmaxf(mt, __shfl_xor(mt, 2, 64));
            mt = fmaxf(mt, __shfl_xor(mt, 4, 64));
            mt = fmaxf(mt, __shfl_xor(mt, 8, 64));
            float mn = fmaxf(m_run[v], mt);
            float alpha = __expf(m_run[v] - mn);
            m_run[v] = mn;
            float p0 = __expf(s0 - mn), p1 = __expf(s1 - mn);
            float p2 = __expf(s2 - mn), p3 = __expf(s3 - mn);
            float ps = (p0 + p1) + (p2 + p3);
            ps += __shfl_xor(ps, 1, 64);
            ps += __shfl_xor(ps, 2, 64);
            ps += __shfl_xor(ps, 4, 64);
            ps += __shfl_xor(ps, 8, 64);
            l_run[v] = l_run[v] * alpha + ps;
            int row = quad * 4 + v;
            Ps[w][row][r]      = f2bf(p0);
            Ps[w][row][16 + r] = f2bf(p1);
            Ps[w][row][32 + r] = f2bf(p2);
            Ps[w][row][48 + r] = f2bf(p3);
            o_acc[0][v] *= alpha; o_acc[1][v] *= alpha;
            o_acc[2][v] *= alpha; o_acc[3][v] *= alpha;
        }

        // PV: A = P (LDS round-trip to A-layout), B = VsT rows
        short8 ap0 = *reinterpret_cast<const short8*>(&Ps[w][r][quad * 8]);
        short8 ap1 = *reinterpret_cast<const short8*>(&Ps[w][r][32 + quad * 8]);
        #pragma unroll
        for (int nt = 0; nt < 4; ++nt) {
            short8 bv0 = *reinterpret_cast<const short8*>(&VsT[nt * 16 + r][quad * 8]);
            short8 bv1 = *reinterpret_cast<const short8*>(&VsT[nt * 16 + r][32 + quad * 8]);
            o_acc[nt] = __builtin_amdgcn_mfma_f32_16x16x32_bf16(ap0, bv0, o_acc[nt], 0, 0, 0);
            o_acc[nt] = __builtin_amdgcn_mfma_f32_16x16x32_bf16(ap1, bv1, o_acc[nt], 0, 0, 0);
        }
    }

    // epilogue: O[row=quad*4+v][col=nt*16+r] / l
    #pragma unroll
    for (int v = 0; v < 4; ++v) {
        float inv = 1.0f / l_run[v];
        int q = q0 + w * 16 + quad * 4 + v;
        __hip_bfloat16* orow = ctx + bbase + (size_t)q * EMBED + hoff;
        #pragma unroll
        for (int nt = 0; nt < 4; ++nt)
            orow[nt * 16 + r] = f2bf(o_acc[nt][v] * inv);
    }
}

// ---------------- fused residual-add + LayerNorm ----------------
__device__ inline float block_reduce_sum(float v, float* sbuf) {
    #pragma unroll
    for (int off = 32; off; off >>= 1) v += __shfl_xor(v, off, 64);
    int wave = threadIdx.x >> 6;
    if ((threadIdx.x & 63) == 0) sbuf[wave] = v;
    __syncthreads();
    float r = sbuf[0] + sbuf[1] + sbuf[2] + sbuf[3];
    __syncthreads();
    return r;
}

__global__ __launch_bounds__(256) void add_ln_kernel(
    const void* __restrict__ X,
    const __hip_bfloat16* __restrict__ Y,
    const void* __restrict__ g,
    const void* __restrict__ bt,
    void* __restrict__ out,
    int x_ext, int out_ext, const int* __restrict__ dflag)
{
    __shared__ float sbuf[4];
    const int f32 = *dflag;
    const bool x32 = (x_ext != 0) && (f32 != 0);
    const bool o32 = (out_ext != 0) && (f32 != 0);
    const int row = blockIdx.x;
    const size_t base = (size_t)row * EMBED;
    const int t = threadIdx.x;

    float xa = x32 ? ((const float*)X)[base + t]
                   : bf2f(((const __hip_bfloat16*)X)[base + t]);
    float xb = x32 ? ((const float*)X)[base + t + 256]
                   : bf2f(((const __hip_bfloat16*)X)[base + t + 256]);
    float x0 = xa + bf2f(Y[base + t]);
    float x1 = xb + bf2f(Y[base + t + 256]);
    float s = block_reduce_sum(x0 + x1, sbuf);
    float mu = s * (1.0f / EMBED);
    float d0 = x0 - mu, d1 = x1 - mu;
    float vs = block_reduce_sum(d0 * d0 + d1 * d1, sbuf);
    float rstd = rsqrtf(vs * (1.0f / EMBED) + LN_EPS);

    float g0 = f32 ? ((const float*)g)[t]        : bf2f(((const __hip_bfloat16*)g)[t]);
    float g1v = f32 ? ((const float*)g)[t + 256] : bf2f(((const __hip_bfloat16*)g)[t + 256]);
    float b0 = f32 ? ((const float*)bt)[t]        : bf2f(((const __hip_bfloat16*)bt)[t]);
    float b1v = f32 ? ((const float*)bt)[t + 256] : bf2f(((const __hip_bfloat16*)bt)[t + 256]);

    float o0 = d0 * rstd * g0 + b0;
    float o1 = d1 * rstd * g1v + b1v;
    if (o32) {
        ((float*)out)[base + t] = o0;
        ((float*)out)[base + t + 256] = o1;
    } else {
        ((__hip_bfloat16*)out)[base + t] = f2bf(o0);
        ((__hip_bfloat16*)out)[base + t + 256] = f2bf(o1);
    }
}

// ---------------- launch ----------------
extern "C" void kernel_launch(void* const* d_in, const int* in_sizes, int n_in,
                              void* d_out, int out_size, void* d_ws, size_t ws_size,
                              hipStream_t stream)
{
    (void)in_sizes; (void)n_in; (void)out_size; (void)ws_size;

    const void* query = d_in[0];
    const void* keyi  = d_in[1];
    const void* vali  = d_in[2];
    const void* Wq = d_in[3];  const void* bq = d_in[4];
    const void* Wk = d_in[5];  const void* bk = d_in[6];
    const void* Wv = d_in[7];  const void* bv = d_in[8];
    const void* Wo = d_in[9];  const void* bo = d_in[10];
    const void* g1 = d_in[11]; const void* be1 = d_in[12];
    const void* g2 = d_in[13]; const void* be2 = d_in[14];
    const void* W1 = d_in[15]; const void* b1 = d_in[16];
    const void* W2 = d_in[17]; const void* b2 = d_in[18];

    int* dflag = (int*)d_ws;
    __hip_bfloat16* p = (__hip_bfloat16*)((char*)d_ws + 64);
    __hip_bfloat16* WqT = p;
    __hip_bfloat16* WkT = WqT + 512 * 512;
    __hip_bfloat16* WvT = WkT + 512 * 512;
    __hip_bfloat16* WoT = WvT + 512 * 512;
    __hip_bfloat16* W1T = WoT + 512 * 512;
    __hip_bfloat16* W2T = W1T + 512 * 2048;
    __hip_bfloat16* buf = W2T + 512 * 2048;
    const size_t NB = (size_t)MROWS * EMBED;     // 4M elems
    __hip_bfloat16* Qb  = buf;
    __hip_bfloat16* Kb  = buf + NB;
    __hip_bfloat16* Vt  = buf + 2 * NB;          // head-transposed V [B*H][64][2048]
    __hip_bfloat16* ctx = buf + 3 * NB;
    __hip_bfloat16* prj = Qb;                    // aliases, lifetimes disjoint
    __hip_bfloat16* x1  = Kb;
    __hip_bfloat16* hbf = Vt;                    // 16M elems: buf2..buf5

    detect_kernel<<<1, 64, 0, stream>>>(query, dflag);

    transpose_cvt_kernel<<<512 * 512 / 256, 256, 0, stream>>>(Wq, WqT, 512, 9, dflag);
    transpose_cvt_kernel<<<512 * 512 / 256, 256, 0, stream>>>(Wk, WkT, 512, 9, dflag);
    transpose_cvt_kernel<<<512 * 512 / 256, 256, 0, stream>>>(Wv, WvT, 512, 9, dflag);
    transpose_cvt_kernel<<<512 * 512 / 256, 256, 0, stream>>>(Wo, WoT, 512, 9, dflag);
    transpose_cvt_kernel<<<512 * 2048 / 256, 256, 0, stream>>>(W1, W1T, 512, 11, dflag);
    transpose_cvt_kernel<<<512 * 2048 / 256, 256, 0, stream>>>(W2, W2T, 2048, 9, dflag);

    gemm_bt_kernel<0,0><<<dim3(MROWS / 128, EMBED / 128), 256, 0, stream>>>(query, WqT, bq, Qb, MROWS, EMBED, EMBED, 1, dflag);
    gemm_bt_kernel<0,0><<<dim3(MROWS / 128, EMBED / 128), 256, 0, stream>>>(keyi,  WkT, bk, Kb, MROWS, EMBED, EMBED, 1, dflag);
    gemm_bt_kernel<0,1><<<dim3(MROWS / 128, EMBED / 128), 256, 0, stream>>>(vali,  WvT, bv, Vt, MROWS, EMBED, EMBED, 1, dflag);

    attn_mfma_kernel<<<dim3(SS / 64, BB * NHEAD), 256, 0, stream>>>(Qb, Kb, Vt, ctx);

    gemm_bt_kernel<0,0><<<dim3(MROWS / 128, EMBED / 128), 256, 0, stream>>>(ctx, WoT, bo, prj, MROWS, EMBED, EMBED, 0, dflag);
    add_ln_kernel<<<MROWS, 256, 0, stream>>>(query, prj, g1, be1, x1, 1, 0, dflag);

    gemm_bt_kernel<1,0><<<dim3(MROWS / 128, FFN / 128), 256, 0, stream>>>(x1, W1T, b1, hbf, MROWS, FFN, EMBED, 0, dflag);
    gemm_bt_kernel<0,0><<<dim3(MROWS / 128, EMBED / 128), 256, 0, stream>>>(hbf, W2T, b2, prj, MROWS, EMBED, FFN, 0, dflag);
    add_ln_kernel<<<MROWS, 256, 0, stream>>>(x1, prj, g2, be2, d_out, 0, 1, dflag);
}

// Round 5
// 481.351 us; speedup vs baseline: 3.5071x; 1.1023x over previous
//
#include <hip/hip_runtime.h>
#include <hip/hip_bf16.h>
#include <math.h>

// Problem constants
#define EMBED 512
#define NHEAD 8
#define HDIM 64
#define FFN 2048
#define BB 4
#define SS 2048
#define MROWS (BB*SS)   // 8192
#define LN_EPS 1e-5f

typedef __attribute__((ext_vector_type(8))) short short8;
typedef __attribute__((ext_vector_type(4))) float floatx4;

__device__ inline float bf2f(__hip_bfloat16 x) { return __bfloat162float(x); }
__device__ inline __hip_bfloat16 f2bf(float x) { return __float2bfloat16(x); }

__device__ inline float gelu_f(float x) {
    return 0.5f * x * (1.0f + erff(x * 0.70710678118654752f));
}

// async 16B global->LDS copy; lds base must be wave-uniform (lane spreads +16B each)
__device__ inline void async_copy16(const void* g, void* l) {
    __builtin_amdgcn_global_load_lds(
        (const __attribute__((address_space(1))) void*)g,
        (__attribute__((address_space(3))) void*)l, 16, 0, 0);
}

// ---------------- runtime dtype detection ----------------
__global__ void detect_kernel(const void* __restrict__ q, int* __restrict__ flag) {
    const float* qf = (const float*)q;
    int lane = threadIdx.x;          // 64 threads
    float v = qf[lane * 1024 + 7];
    bool ok = (v == v) && (fabsf(v) > 0x1p-40f) && (fabsf(v) < 0x1p40f);
    unsigned long long m = __ballot(ok);
    if (lane == 0) *flag = (__popcll(m) >= 32) ? 1 : 0;
}

// ---------------- weight transpose+convert: src[R][C] -> dst[C][R] (bf16) ----------------
__global__ __launch_bounds__(256) void transpose_cvt_kernel(
    const void* __restrict__ src, __hip_bfloat16* __restrict__ dst,
    int R, int logC, const int* __restrict__ dflag)
{
    const int f32 = *dflag;
    int i = blockIdx.x * 256 + threadIdx.x;
    int C = 1 << logC;
    if (i < (R << logC)) {
        int r = i >> logC, c = i & (C - 1);
        __hip_bfloat16 v = f32 ? f2bf(((const float*)src)[i])
                               : ((const __hip_bfloat16*)src)[i];
        dst[(size_t)c * R + r] = v;
    }
}

// merged 4x (512x512) transpose: blockIdx.y selects the weight
__global__ __launch_bounds__(256) void transpose4_kernel(
    const void* __restrict__ s0, const void* __restrict__ s1,
    const void* __restrict__ s2, const void* __restrict__ s3,
    __hip_bfloat16* __restrict__ d0, __hip_bfloat16* __restrict__ d1,
    __hip_bfloat16* __restrict__ d2, __hip_bfloat16* __restrict__ d3,
    const int* __restrict__ dflag)
{
    const int f32 = *dflag;
    const int which = blockIdx.y;
    const void* src = which == 0 ? s0 : which == 1 ? s1 : which == 2 ? s2 : s3;
    __hip_bfloat16* dst = which == 0 ? d0 : which == 1 ? d1 : which == 2 ? d2 : d3;
    int i = blockIdx.x * 256 + threadIdx.x;   // grid.x = 512*512/256
    int r = i >> 9, c = i & 511;
    __hip_bfloat16 v = f32 ? f2bf(((const float*)src)[i])
                           : ((const __hip_bfloat16*)src)[i];
    dst[(size_t)c * 512 + r] = v;
}

// ---------------- GEMM (VGPR staging, dual-dtype A): C = A @ Bt^T + bias ----------------
// used for QKV projections (A = external fp32/bf16 input)
__global__ __launch_bounds__(256) void gemm_bt_kernel(
    const void* __restrict__ Ax,
    const __hip_bfloat16* __restrict__ Bt,
    const void* __restrict__ bias,
    __hip_bfloat16* __restrict__ C,
    int M, int N, int K, const int* __restrict__ dflag)
{
    const int f32 = *dflag;
    const __hip_bfloat16* Ab = (const __hip_bfloat16*)Ax;
    const float* Af = (const float*)Ax;

    const int bm = blockIdx.x * 128;
    const int bn = blockIdx.y * 128;
    const int t = threadIdx.x;
    const int wave = t >> 6, lane = t & 63;
    const int wm = (wave >> 1) * 64, wn = (wave & 1) * 64;
    const int quad = lane >> 4, r = lane & 15;

    __shared__ alignas(16) __hip_bfloat16 As[128][40];
    __shared__ alignas(16) __hip_bfloat16 Bs[128][40];

    floatx4 acc[4][4];
    #pragma unroll
    for (int i = 0; i < 4; ++i)
        #pragma unroll
        for (int j = 0; j < 4; ++j)
            acc[i][j] = (floatx4){0.f, 0.f, 0.f, 0.f};

    const int srow = t >> 2;
    const int scol = (t & 3) * 8;

    for (int kt = 0; kt < K; kt += 32) {
        #pragma unroll
        for (int it = 0; it < 2; ++it) {
            int row = srow + it * 64;
            if (f32) {
                const float* src = Af + (size_t)(bm + row) * K + kt + scol;
                float4 f0 = *reinterpret_cast<const float4*>(src);
                float4 f1 = *reinterpret_cast<const float4*>(src + 4);
                alignas(16) __hip_bfloat16 h[8] = {
                    f2bf(f0.x), f2bf(f0.y), f2bf(f0.z), f2bf(f0.w),
                    f2bf(f1.x), f2bf(f1.y), f2bf(f1.z), f2bf(f1.w)};
                *reinterpret_cast<uint4*>(&As[row][scol]) = *reinterpret_cast<const uint4*>(h);
            } else {
                uint4 av = *reinterpret_cast<const uint4*>(Ab + (size_t)(bm + row) * K + kt + scol);
                *reinterpret_cast<uint4*>(&As[row][scol]) = av;
            }
            uint4 bv = *reinterpret_cast<const uint4*>(Bt + (size_t)(bn + row) * K + kt + scol);
            *reinterpret_cast<uint4*>(&Bs[row][scol]) = bv;
        }
        __syncthreads();
        short8 af[4], bfr[4];
        #pragma unroll
        for (int i = 0; i < 4; ++i)
            af[i] = *reinterpret_cast<const short8*>(&As[wm + i * 16 + r][quad * 8]);
        #pragma unroll
        for (int j = 0; j < 4; ++j)
            bfr[j] = *reinterpret_cast<const short8*>(&Bs[wn + j * 16 + r][quad * 8]);
        #pragma unroll
        for (int i = 0; i < 4; ++i)
            #pragma unroll
            for (int j = 0; j < 4; ++j)
                acc[i][j] = __builtin_amdgcn_mfma_f32_16x16x32_bf16(af[i], bfr[j], acc[i][j], 0, 0, 0);
        __syncthreads();
    }

    #pragma unroll
    for (int j = 0; j < 4; ++j) {
        const int n = bn + wn + j * 16 + r;
        const float bvv = f32 ? ((const float*)bias)[n]
                              : bf2f(((const __hip_bfloat16*)bias)[n]);
        #pragma unroll
        for (int i = 0; i < 4; ++i) {
            #pragma unroll
            for (int v = 0; v < 4; ++v) {
                int m = bm + wm + i * 16 + quad * 4 + v;
                C[(size_t)m * N + n] = f2bf(acc[i][j][v] + bvv);
            }
        }
    }
}

// ---------------- GEMM (global_load_lds staging, bf16 A): the m97 pattern ----------------
// 128x128 tile, BK=32, unpadded LDS tiles (layout dictated by lane-contiguous async copy)
template<int ACT>
__global__ __launch_bounds__(256) void gemm_bt_lds_kernel(
    const __hip_bfloat16* __restrict__ A,
    const __hip_bfloat16* __restrict__ Bt,
    const void* __restrict__ bias,
    __hip_bfloat16* __restrict__ C,
    int M, int N, int K, const int* __restrict__ dflag)
{
    const int f32 = *dflag;
    const int bm = blockIdx.x * 128;
    const int bn = blockIdx.y * 128;
    const int t = threadIdx.x;
    const int wave = t >> 6, lane = t & 63;
    const int wm = (wave >> 1) * 64, wn = (wave & 1) * 64;
    const int quad = lane >> 4, r = lane & 15;

    __shared__ alignas(16) __hip_bfloat16 As[128 * 32];
    __shared__ alignas(16) __hip_bfloat16 Bs[128 * 32];

    floatx4 acc[4][4];
    #pragma unroll
    for (int i = 0; i < 4; ++i)
        #pragma unroll
        for (int j = 0; j < 4; ++j)
            acc[i][j] = (floatx4){0.f, 0.f, 0.f, 0.f};

    // wave-instr chunk: c = wave*128 + it*64 + lane; row = c>>2, col = (c&3)*8
    const int c0 = wave * 128;

    for (int kt = 0; kt < K; kt += 32) {
        #pragma unroll
        for (int it = 0; it < 2; ++it) {
            int c = c0 + it * 64 + lane;
            int row = c >> 2, col = (c & 3) * 8;
            async_copy16(A + (size_t)(bm + row) * K + kt + col,
                         As + (size_t)(c0 + it * 64) * 8);
            async_copy16(Bt + (size_t)(bn + row) * K + kt + col,
                         Bs + (size_t)(c0 + it * 64) * 8);
        }
        __syncthreads();   // drains vmcnt -> LDS tiles complete
        short8 af[4], bfr[4];
        #pragma unroll
        for (int i = 0; i < 4; ++i)
            af[i] = *reinterpret_cast<const short8*>(&As[(wm + i * 16 + r) * 32 + quad * 8]);
        #pragma unroll
        for (int j = 0; j < 4; ++j)
            bfr[j] = *reinterpret_cast<const short8*>(&Bs[(wn + j * 16 + r) * 32 + quad * 8]);
        #pragma unroll
        for (int i = 0; i < 4; ++i)
            #pragma unroll
            for (int j = 0; j < 4; ++j)
                acc[i][j] = __builtin_amdgcn_mfma_f32_16x16x32_bf16(af[i], bfr[j], acc[i][j], 0, 0, 0);
        __syncthreads();
    }

    #pragma unroll
    for (int j = 0; j < 4; ++j) {
        const int n = bn + wn + j * 16 + r;
        const float bvv = f32 ? ((const float*)bias)[n]
                              : bf2f(((const __hip_bfloat16*)bias)[n]);
        #pragma unroll
        for (int i = 0; i < 4; ++i) {
            #pragma unroll
            for (int v = 0; v < 4; ++v) {
                int m = bm + wm + i * 16 + quad * 4 + v;
                float x = acc[i][j][v] + bvv;
                if (ACT == 1) x = gelu_f(x);
                C[(size_t)m * N + n] = f2bf(x);
            }
        }
    }
}

// ---------------- V head-transpose: Vb[B*S][E] -> Vt[B*H][64 d][2048 s] ----------------
__global__ __launch_bounds__(256) void vtrans_kernel(
    const __hip_bfloat16* __restrict__ Vb, __hip_bfloat16* __restrict__ Vt)
{
    const int bh = blockIdx.y;               // b*8+h
    const int b = bh >> 3, h = bh & 7;
    const int s0 = blockIdx.x * 64;
    __shared__ alignas(16) __hip_bfloat16 L[64][72];
    const int t = threadIdx.x;
    for (int c = t; c < 512; c += 256) {
        int row = c >> 3, g = c & 7;
        *reinterpret_cast<uint4*>(&L[row][g * 8]) =
            *reinterpret_cast<const uint4*>(Vb + (size_t)(b * SS + s0 + row) * EMBED + h * 64 + g * 8);
    }
    __syncthreads();
    for (int c = t; c < 512; c += 256) {
        int d = c >> 3, g = c & 7;
        alignas(16) __hip_bfloat16 tmp[8];
        #pragma unroll
        for (int j = 0; j < 8; ++j) tmp[j] = L[g * 8 + j][d];
        *reinterpret_cast<uint4*>(Vt + ((size_t)bh * 64 + d) * SS + s0 + g * 8) =
            *reinterpret_cast<const uint4*>(tmp);
    }
}

// ---------------- MFMA flash attention ----------------
__global__ __launch_bounds__(256) void attn_mfma_kernel(
    const __hip_bfloat16* __restrict__ Qg,
    const __hip_bfloat16* __restrict__ Kg,
    const __hip_bfloat16* __restrict__ Vt,
    __hip_bfloat16* __restrict__ ctx)
{
    const int bh = blockIdx.y;
    const int b = bh >> 3, h = bh & 7;
    const int q0 = blockIdx.x * 64;
    const int t = threadIdx.x;
    const int w = t >> 6, lane = t & 63;
    const int quad = lane >> 4, r = lane & 15;

    __shared__ alignas(16) __hip_bfloat16 Ks[64][72];
    __shared__ alignas(16) __hip_bfloat16 VsT[64][72];
    __shared__ alignas(16) __hip_bfloat16 Ps[4][16][72];

    const size_t bbase = (size_t)b * SS * EMBED;
    const size_t hoff = (size_t)h * HDIM;
    const size_t vtbase = (size_t)bh * HDIM * SS;

    short8 aq[2];
    {
        const __hip_bfloat16* qrow = Qg + bbase + (size_t)(q0 + w * 16 + r) * EMBED + hoff;
        aq[0] = *reinterpret_cast<const short8*>(qrow + quad * 8);
        aq[1] = *reinterpret_cast<const short8*>(qrow + 32 + quad * 8);
    }

    float m_run[4] = {-1e30f, -1e30f, -1e30f, -1e30f};
    float l_run[4] = {0.f, 0.f, 0.f, 0.f};
    floatx4 o_acc[4];
    #pragma unroll
    for (int nt = 0; nt < 4; ++nt) o_acc[nt] = (floatx4){0.f, 0.f, 0.f, 0.f};

    for (int kt = 0; kt < SS; kt += 64) {
        __syncthreads();
        #pragma unroll
        for (int c = t; c < 512; c += 256) {
            int row = c >> 3, col = (c & 7) * 8;
            *reinterpret_cast<uint4*>(&Ks[row][col]) =
                *reinterpret_cast<const uint4*>(Kg + bbase + (size_t)(kt + row) * EMBED + hoff + col);
            *reinterpret_cast<uint4*>(&VsT[row][col]) =
                *reinterpret_cast<const uint4*>(Vt + vtbase + (size_t)row * SS + kt + col);
        }
        __syncthreads();

        floatx4 sc[4];
        #pragma unroll
        for (int nt = 0; nt < 4; ++nt) sc[nt] = (floatx4){0.f, 0.f, 0.f, 0.f};
        #pragma unroll
        for (int nt = 0; nt < 4; ++nt) {
            short8 bk0 = *reinterpret_cast<const short8*>(&Ks[nt * 16 + r][quad * 8]);
            short8 bk1 = *reinterpret_cast<const short8*>(&Ks[nt * 16 + r][32 + quad * 8]);
            sc[nt] = __builtin_amdgcn_mfma_f32_16x16x32_bf16(aq[0], bk0, sc[nt], 0, 0, 0);
            sc[nt] = __builtin_amdgcn_mfma_f32_16x16x32_bf16(aq[1], bk1, sc[nt], 0, 0, 0);
        }

        #pragma unroll
        for (int v = 0; v < 4; ++v) {
            float s0 = sc[0][v] * 0.125f, s1 = sc[1][v] * 0.125f;
            float s2 = sc[2][v] * 0.125f, s3 = sc[3][v] * 0.125f;
            float mt = fmaxf(fmaxf(s0, s1), fmaxf(s2, s3));
            mt = fmaxf(mt, __shfl_xor(mt, 1, 64));
            mt = fmaxf(mt, __shfl_xor(mt, 2, 64));
            mt = fmaxf(mt, __shfl_xor(mt, 4, 64));
            mt = fmaxf(mt, __shfl_xor(mt, 8, 64));
            float mn = fmaxf(m_run[v], mt);
            float alpha = __expf(m_run[v] - mn);
            m_run[v] = mn;
            float p0 = __expf(s0 - mn), p1 = __expf(s1 - mn);
            float p2 = __expf(s2 - mn), p3 = __expf(s3 - mn);
            float ps = (p0 + p1) + (p2 + p3);
            ps += __shfl_xor(ps, 1, 64);
            ps += __shfl_xor(ps, 2, 64);
            ps += __shfl_xor(ps, 4, 64);
            ps += __shfl_xor(ps, 8, 64);
            l_run[v] = l_run[v] * alpha + ps;
            int row = quad * 4 + v;
            Ps[w][row][r]      = f2bf(p0);
            Ps[w][row][16 + r] = f2bf(p1);
            Ps[w][row][32 + r] = f2bf(p2);
            Ps[w][row][48 + r] = f2bf(p3);
            o_acc[0][v] *= alpha; o_acc[1][v] *= alpha;
            o_acc[2][v] *= alpha; o_acc[3][v] *= alpha;
        }

        short8 ap0 = *reinterpret_cast<const short8*>(&Ps[w][r][quad * 8]);
        short8 ap1 = *reinterpret_cast<const short8*>(&Ps[w][r][32 + quad * 8]);
        #pragma unroll
        for (int nt = 0; nt < 4; ++nt) {
            short8 bv0 = *reinterpret_cast<const short8*>(&VsT[nt * 16 + r][quad * 8]);
            short8 bv1 = *reinterpret_cast<const short8*>(&VsT[nt * 16 + r][32 + quad * 8]);
            o_acc[nt] = __builtin_amdgcn_mfma_f32_16x16x32_bf16(ap0, bv0, o_acc[nt], 0, 0, 0);
            o_acc[nt] = __builtin_amdgcn_mfma_f32_16x16x32_bf16(ap1, bv1, o_acc[nt], 0, 0, 0);
        }
    }

    #pragma unroll
    for (int v = 0; v < 4; ++v) {
        float inv = 1.0f / l_run[v];
        int q = q0 + w * 16 + quad * 4 + v;
        __hip_bfloat16* orow = ctx + bbase + (size_t)q * EMBED + hoff;
        #pragma unroll
        for (int nt = 0; nt < 4; ++nt)
            orow[nt * 16 + r] = f2bf(o_acc[nt][v] * inv);
    }
}

// ---------------- fused residual-add + LayerNorm ----------------
__device__ inline float block_reduce_sum(float v, float* sbuf) {
    #pragma unroll
    for (int off = 32; off; off >>= 1) v += __shfl_xor(v, off, 64);
    int wave = threadIdx.x >> 6;
    if ((threadIdx.x & 63) == 0) sbuf[wave] = v;
    __syncthreads();
    float r = sbuf[0] + sbuf[1] + sbuf[2] + sbuf[3];
    __syncthreads();
    return r;
}

__global__ __launch_bounds__(256) void add_ln_kernel(
    const void* __restrict__ X,
    const __hip_bfloat16* __restrict__ Y,
    const void* __restrict__ g,
    const void* __restrict__ bt,
    void* __restrict__ out,
    int x_ext, int out_ext, const int* __restrict__ dflag)
{
    __shared__ float sbuf[4];
    const int f32 = *dflag;
    const bool x32 = (x_ext != 0) && (f32 != 0);
    const bool o32 = (out_ext != 0) && (f32 != 0);
    const int row = blockIdx.x;
    const size_t base = (size_t)row * EMBED;
    const int t = threadIdx.x;

    float xa = x32 ? ((const float*)X)[base + t]
                   : bf2f(((const __hip_bfloat16*)X)[base + t]);
    float xb = x32 ? ((const float*)X)[base + t + 256]
                   : bf2f(((const __hip_bfloat16*)X)[base + t + 256]);
    float x0 = xa + bf2f(Y[base + t]);
    float x1 = xb + bf2f(Y[base + t + 256]);
    float s = block_reduce_sum(x0 + x1, sbuf);
    float mu = s * (1.0f / EMBED);
    float d0 = x0 - mu, d1 = x1 - mu;
    float vs = block_reduce_sum(d0 * d0 + d1 * d1, sbuf);
    float rstd = rsqrtf(vs * (1.0f / EMBED) + LN_EPS);

    float g0 = f32 ? ((const float*)g)[t]        : bf2f(((const __hip_bfloat16*)g)[t]);
    float g1v = f32 ? ((const float*)g)[t + 256] : bf2f(((const __hip_bfloat16*)g)[t + 256]);
    float b0 = f32 ? ((const float*)bt)[t]        : bf2f(((const __hip_bfloat16*)bt)[t]);
    float b1v = f32 ? ((const float*)bt)[t + 256] : bf2f(((const __hip_bfloat16*)bt)[t + 256]);

    float o0 = d0 * rstd * g0 + b0;
    float o1 = d1 * rstd * g1v + b1v;
    if (o32) {
        ((float*)out)[base + t] = o0;
        ((float*)out)[base + t + 256] = o1;
    } else {
        ((__hip_bfloat16*)out)[base + t] = f2bf(o0);
        ((__hip_bfloat16*)out)[base + t + 256] = f2bf(o1);
    }
}

// ---------------- launch ----------------
extern "C" void kernel_launch(void* const* d_in, const int* in_sizes, int n_in,
                              void* d_out, int out_size, void* d_ws, size_t ws_size,
                              hipStream_t stream)
{
    (void)in_sizes; (void)n_in; (void)out_size; (void)ws_size;

    const void* query = d_in[0];
    const void* keyi  = d_in[1];
    const void* vali  = d_in[2];
    const void* Wq = d_in[3];  const void* bq = d_in[4];
    const void* Wk = d_in[5];  const void* bk = d_in[6];
    const void* Wv = d_in[7];  const void* bv = d_in[8];
    const void* Wo = d_in[9];  const void* bo = d_in[10];
    const void* g1 = d_in[11]; const void* be1 = d_in[12];
    const void* g2 = d_in[13]; const void* be2 = d_in[14];
    const void* W1 = d_in[15]; const void* b1 = d_in[16];
    const void* W2 = d_in[17]; const void* b2 = d_in[18];

    // ---- workspace: 64B flag + 6MB weightsT + 6 x 8MB units = 54 MB ----
    int* dflag = (int*)d_ws;
    __hip_bfloat16* p = (__hip_bfloat16*)((char*)d_ws + 64);
    __hip_bfloat16* WqT = p;
    __hip_bfloat16* WkT = WqT + 512 * 512;
    __hip_bfloat16* WvT = WkT + 512 * 512;
    __hip_bfloat16* WoT = WvT + 512 * 512;
    __hip_bfloat16* W1T = WoT + 512 * 512;
    __hip_bfloat16* W2T = W1T + 512 * 2048;
    __hip_bfloat16* buf = W2T + 512 * 2048;
    const size_t NB = (size_t)MROWS * EMBED;     // 4M elems
    __hip_bfloat16* Qb   = buf;                  // unit0
    __hip_bfloat16* Kb   = buf + NB;             // unit1
    __hip_bfloat16* Vb   = buf + 2 * NB;         // unit2
    __hip_bfloat16* Vt   = buf + 3 * NB;         // unit3
    __hip_bfloat16* ctx  = buf + 4 * NB;         // unit4
    __hip_bfloat16* prj  = buf + 5 * NB;         // unit5
    // aliases (disjoint lifetimes):
    __hip_bfloat16* x1   = ctx;                  // unit4 (ctx dead after Wo GEMM)
    __hip_bfloat16* hbf  = Qb;                   // units 0..3 (all dead by FFN1)
    __hip_bfloat16* prj2 = prj;                  // unit5 (prj dead after LN1)

    detect_kernel<<<1, 64, 0, stream>>>(query, dflag);

    transpose4_kernel<<<dim3(512 * 512 / 256, 4), 256, 0, stream>>>(
        Wq, Wk, Wv, Wo, WqT, WkT, WvT, WoT, dflag);
    transpose_cvt_kernel<<<512 * 2048 / 256, 256, 0, stream>>>(W1, W1T, 512, 11, dflag);
    transpose_cvt_kernel<<<512 * 2048 / 256, 256, 0, stream>>>(W2, W2T, 2048, 9, dflag);

    // QKV projections (dual-dtype A path)
    gemm_bt_kernel<<<dim3(MROWS / 128, EMBED / 128), 256, 0, stream>>>(query, WqT, bq, Qb, MROWS, EMBED, EMBED, dflag);
    gemm_bt_kernel<<<dim3(MROWS / 128, EMBED / 128), 256, 0, stream>>>(keyi,  WkT, bk, Kb, MROWS, EMBED, EMBED, dflag);
    gemm_bt_kernel<<<dim3(MROWS / 128, EMBED / 128), 256, 0, stream>>>(vali,  WvT, bv, Vb, MROWS, EMBED, EMBED, dflag);

    // V head-transpose (coalesced LDS-tiled)
    vtrans_kernel<<<dim3(SS / 64, BB * NHEAD), 256, 0, stream>>>(Vb, Vt);

    // attention
    attn_mfma_kernel<<<dim3(SS / 64, BB * NHEAD), 256, 0, stream>>>(Qb, Kb, Vt, ctx);

    // output projection + LN1
    gemm_bt_lds_kernel<0><<<dim3(MROWS / 128, EMBED / 128), 256, 0, stream>>>(ctx, WoT, bo, prj, MROWS, EMBED, EMBED, dflag);
    add_ln_kernel<<<MROWS, 256, 0, stream>>>(query, prj, g1, be1, x1, 1, 0, dflag);

    // FFN
    gemm_bt_lds_kernel<1><<<dim3(MROWS / 128, FFN / 128), 256, 0, stream>>>(x1, W1T, b1, hbf, MROWS, FFN, EMBED, dflag);
    gemm_bt_lds_kernel<0><<<dim3(MROWS / 128, EMBED / 128), 256, 0, stream>>>(hbf, W2T, b2, prj2, MROWS, EMBED, FFN, dflag);
    add_ln_kernel<<<MROWS, 256, 0, stream>>>(x1, prj2, g2, be2, d_out, 0, 1, dflag);
}

// Round 6
// 451.575 us; speedup vs baseline: 3.7384x; 1.0659x over previous
//
#include <hip/hip_runtime.h>
#include <hip/hip_bf16.h>
#include <math.h>

// Problem constants
#define EMBED 512
#define NHEAD 8
#define HDIM 64
#define FFN 2048
#define BB 4
#define SS 2048
#define MROWS (BB*SS)   // 8192
#define LN_EPS 1e-5f

typedef __attribute__((ext_vector_type(8))) short short8;
typedef __attribute__((ext_vector_type(4))) float floatx4;

__device__ inline float bf2f(__hip_bfloat16 x) { return __bfloat162float(x); }
__device__ inline __hip_bfloat16 f2bf(float x) { return __float2bfloat16(x); }

__device__ inline float gelu_f(float x) {
    return 0.5f * x * (1.0f + erff(x * 0.70710678118654752f));
}

// async 16B global->LDS copy; lds base must be wave-uniform (lane spreads +16B each)
__device__ inline void async_copy16(const void* g, void* l) {
    __builtin_amdgcn_global_load_lds(
        (const __attribute__((address_space(1))) void*)g,
        (__attribute__((address_space(3))) void*)l, 16, 0, 0);
}

// ---------------- runtime dtype detection ----------------
__global__ void detect_kernel(const void* __restrict__ q, int* __restrict__ flag) {
    const float* qf = (const float*)q;
    int lane = threadIdx.x;          // 64 threads
    float v = qf[lane * 1024 + 7];
    bool ok = (v == v) && (fabsf(v) > 0x1p-40f) && (fabsf(v) < 0x1p40f);
    unsigned long long m = __ballot(ok);
    if (lane == 0) *flag = (__popcll(m) >= 32) ? 1 : 0;
}

// ---------------- LDS-tiled transpose: src[R][C] -> dst[C][R], 64x64 tiles ----------------
__global__ __launch_bounds__(256) void transpose_tile_kernel(
    const void* __restrict__ src, __hip_bfloat16* __restrict__ dst,
    int R, int C, const int* __restrict__ dflag)
{
    const int f32 = *dflag;
    const int r0 = blockIdx.x * 64, c0 = blockIdx.y * 64;
    __shared__ __hip_bfloat16 L[64][65];
    const int t = threadIdx.x;
    for (int c = t; c < 4096; c += 256) {
        int lr = c >> 6, lc = c & 63;
        __hip_bfloat16 v = f32 ? f2bf(((const float*)src)[(size_t)(r0 + lr) * C + c0 + lc])
                               : ((const __hip_bfloat16*)src)[(size_t)(r0 + lr) * C + c0 + lc];
        L[lr][lc] = v;
    }
    __syncthreads();
    for (int c = t; c < 4096; c += 256) {
        int lr = c >> 6, lc = c & 63;   // lr = dst-row-within-tile (= src col)
        dst[(size_t)(c0 + lr) * R + r0 + lc] = L[lc][lr];
    }
}

// ---------------- QKV GEMM (VGPR staging, dual-dtype A): 128M x 64N tile ----------------
// 4 waves (2x2): wave covers 64x32 via 4x2 MFMA 16x16x32 tiles. grid (M/128, N/64).
__global__ __launch_bounds__(256) void gemm_qkv_kernel(
    const void* __restrict__ Ax,
    const __hip_bfloat16* __restrict__ Bt,
    const void* __restrict__ bias,
    __hip_bfloat16* __restrict__ C,
    int M, int N, int K, const int* __restrict__ dflag)
{
    const int f32 = *dflag;
    const __hip_bfloat16* Ab = (const __hip_bfloat16*)Ax;
    const float* Af = (const float*)Ax;

    const int bm = blockIdx.x * 128;
    const int bn = blockIdx.y * 64;
    const int t = threadIdx.x;
    const int wave = t >> 6, lane = t & 63;
    const int wm = (wave >> 1) * 64, wn = (wave & 1) * 32;
    const int quad = lane >> 4, r = lane & 15;

    __shared__ alignas(16) __hip_bfloat16 As[128][40];
    __shared__ alignas(16) __hip_bfloat16 Bs[64][40];

    floatx4 acc[4][2];
    #pragma unroll
    for (int i = 0; i < 4; ++i)
        #pragma unroll
        for (int j = 0; j < 2; ++j)
            acc[i][j] = (floatx4){0.f, 0.f, 0.f, 0.f};

    const int srow = t >> 2;         // 0..63
    const int scol = (t & 3) * 8;

    for (int kt = 0; kt < K; kt += 32) {
        #pragma unroll
        for (int it = 0; it < 2; ++it) {
            int row = srow + it * 64;
            if (f32) {
                const float* src = Af + (size_t)(bm + row) * K + kt + scol;
                float4 f0 = *reinterpret_cast<const float4*>(src);
                float4 f1 = *reinterpret_cast<const float4*>(src + 4);
                alignas(16) __hip_bfloat16 h[8] = {
                    f2bf(f0.x), f2bf(f0.y), f2bf(f0.z), f2bf(f0.w),
                    f2bf(f1.x), f2bf(f1.y), f2bf(f1.z), f2bf(f1.w)};
                *reinterpret_cast<uint4*>(&As[row][scol]) = *reinterpret_cast<const uint4*>(h);
            } else {
                uint4 av = *reinterpret_cast<const uint4*>(Ab + (size_t)(bm + row) * K + kt + scol);
                *reinterpret_cast<uint4*>(&As[row][scol]) = av;
            }
        }
        {   // B tile: 64 rows, one pass
            uint4 bvv = *reinterpret_cast<const uint4*>(Bt + (size_t)(bn + srow) * K + kt + scol);
            *reinterpret_cast<uint4*>(&Bs[srow][scol]) = bvv;
        }
        __syncthreads();
        short8 af[4], bfr[2];
        #pragma unroll
        for (int i = 0; i < 4; ++i)
            af[i] = *reinterpret_cast<const short8*>(&As[wm + i * 16 + r][quad * 8]);
        #pragma unroll
        for (int j = 0; j < 2; ++j)
            bfr[j] = *reinterpret_cast<const short8*>(&Bs[wn + j * 16 + r][quad * 8]);
        #pragma unroll
        for (int i = 0; i < 4; ++i)
            #pragma unroll
            for (int j = 0; j < 2; ++j)
                acc[i][j] = __builtin_amdgcn_mfma_f32_16x16x32_bf16(af[i], bfr[j], acc[i][j], 0, 0, 0);
        __syncthreads();
    }

    #pragma unroll
    for (int j = 0; j < 2; ++j) {
        const int n = bn + wn + j * 16 + r;
        const float bvv = f32 ? ((const float*)bias)[n]
                              : bf2f(((const __hip_bfloat16*)bias)[n]);
        #pragma unroll
        for (int i = 0; i < 4; ++i) {
            #pragma unroll
            for (int v = 0; v < 4; ++v) {
                int m = bm + wm + i * 16 + quad * 4 + v;
                C[(size_t)m * N + n] = f2bf(acc[i][j][v] + bvv);
            }
        }
    }
}

// ---------------- GEMM (async LDS staging, bf16): 128x128 tile (for N>=128 grids) ----------------
template<int ACT>
__global__ __launch_bounds__(256) void gemm_bt_lds_kernel(
    const __hip_bfloat16* __restrict__ A,
    const __hip_bfloat16* __restrict__ Bt,
    const void* __restrict__ bias,
    __hip_bfloat16* __restrict__ C,
    int M, int N, int K, const int* __restrict__ dflag)
{
    const int f32 = *dflag;
    const int bm = blockIdx.x * 128;
    const int bn = blockIdx.y * 128;
    const int t = threadIdx.x;
    const int wave = t >> 6, lane = t & 63;
    const int wm = (wave >> 1) * 64, wn = (wave & 1) * 64;
    const int quad = lane >> 4, r = lane & 15;

    __shared__ alignas(16) __hip_bfloat16 As[128 * 32];
    __shared__ alignas(16) __hip_bfloat16 Bs[128 * 32];

    floatx4 acc[4][4];
    #pragma unroll
    for (int i = 0; i < 4; ++i)
        #pragma unroll
        for (int j = 0; j < 4; ++j)
            acc[i][j] = (floatx4){0.f, 0.f, 0.f, 0.f};

    const int c0 = wave * 128;

    for (int kt = 0; kt < K; kt += 32) {
        #pragma unroll
        for (int it = 0; it < 2; ++it) {
            int c = c0 + it * 64 + lane;
            int row = c >> 2, col = (c & 3) * 8;
            async_copy16(A + (size_t)(bm + row) * K + kt + col,
                         As + (size_t)(c0 + it * 64) * 8);
            async_copy16(Bt + (size_t)(bn + row) * K + kt + col,
                         Bs + (size_t)(c0 + it * 64) * 8);
        }
        __syncthreads();
        short8 af[4], bfr[4];
        #pragma unroll
        for (int i = 0; i < 4; ++i)
            af[i] = *reinterpret_cast<const short8*>(&As[(wm + i * 16 + r) * 32 + quad * 8]);
        #pragma unroll
        for (int j = 0; j < 4; ++j)
            bfr[j] = *reinterpret_cast<const short8*>(&Bs[(wn + j * 16 + r) * 32 + quad * 8]);
        #pragma unroll
        for (int i = 0; i < 4; ++i)
            #pragma unroll
            for (int j = 0; j < 4; ++j)
                acc[i][j] = __builtin_amdgcn_mfma_f32_16x16x32_bf16(af[i], bfr[j], acc[i][j], 0, 0, 0);
        __syncthreads();
    }

    #pragma unroll
    for (int j = 0; j < 4; ++j) {
        const int n = bn + wn + j * 16 + r;
        const float bvv = f32 ? ((const float*)bias)[n]
                              : bf2f(((const __hip_bfloat16*)bias)[n]);
        #pragma unroll
        for (int i = 0; i < 4; ++i) {
            #pragma unroll
            for (int v = 0; v < 4; ++v) {
                int m = bm + wm + i * 16 + quad * 4 + v;
                float x = acc[i][j][v] + bvv;
                if (ACT == 1) x = gelu_f(x);
                C[(size_t)m * N + n] = f2bf(x);
            }
        }
    }
}

// ---------------- GEMM (async LDS staging, bf16): 128M x 64N tile ----------------
// grid (M/128, N/64), 512 blocks for N=512 -> 8 waves/CU
template<int ACT>
__global__ __launch_bounds__(256) void gemm_lds_n64_kernel(
    const __hip_bfloat16* __restrict__ A,
    const __hip_bfloat16* __restrict__ Bt,
    const void* __restrict__ bias,
    __hip_bfloat16* __restrict__ C,
    int M, int N, int K, const int* __restrict__ dflag)
{
    const int f32 = *dflag;
    const int bm = blockIdx.x * 128;
    const int bn = blockIdx.y * 64;
    const int t = threadIdx.x;
    const int wave = t >> 6, lane = t & 63;
    const int wm = (wave >> 1) * 64, wn = (wave & 1) * 32;
    const int quad = lane >> 4, r = lane & 15;

    __shared__ alignas(16) __hip_bfloat16 As[128 * 32];
    __shared__ alignas(16) __hip_bfloat16 Bs[64 * 32];

    floatx4 acc[4][2];
    #pragma unroll
    for (int i = 0; i < 4; ++i)
        #pragma unroll
        for (int j = 0; j < 2; ++j)
            acc[i][j] = (floatx4){0.f, 0.f, 0.f, 0.f};

    for (int kt = 0; kt < K; kt += 32) {
        // 12 chunks of 512 elems: 0..7 -> As, 8..11 -> Bs; wave handles 3
        #pragma unroll
        for (int ci = 0; ci < 3; ++ci) {
            int ch = wave * 3 + ci;
            int isA = (ch < 8);
            int row0 = (isA ? ch : ch - 8) * 16;
            int row = row0 + (lane >> 2), col = (lane & 3) * 8;
            const __hip_bfloat16* src = isA ? (A + (size_t)(bm + row) * K + kt + col)
                                            : (Bt + (size_t)(bn + row) * K + kt + col);
            __hip_bfloat16* ldsb = (isA ? As : Bs) + (size_t)row0 * 32;
            async_copy16(src, ldsb);
        }
        __syncthreads();
        short8 af[4], bfr[2];
        #pragma unroll
        for (int i = 0; i < 4; ++i)
            af[i] = *reinterpret_cast<const short8*>(&As[(wm + i * 16 + r) * 32 + quad * 8]);
        #pragma unroll
        for (int j = 0; j < 2; ++j)
            bfr[j] = *reinterpret_cast<const short8*>(&Bs[(wn + j * 16 + r) * 32 + quad * 8]);
        #pragma unroll
        for (int i = 0; i < 4; ++i)
            #pragma unroll
            for (int j = 0; j < 2; ++j)
                acc[i][j] = __builtin_amdgcn_mfma_f32_16x16x32_bf16(af[i], bfr[j], acc[i][j], 0, 0, 0);
        __syncthreads();
    }

    #pragma unroll
    for (int j = 0; j < 2; ++j) {
        const int n = bn + wn + j * 16 + r;
        const float bvv = f32 ? ((const float*)bias)[n]
                              : bf2f(((const __hip_bfloat16*)bias)[n]);
        #pragma unroll
        for (int i = 0; i < 4; ++i) {
            #pragma unroll
            for (int v = 0; v < 4; ++v) {
                int m = bm + wm + i * 16 + quad * 4 + v;
                float x = acc[i][j][v] + bvv;
                if (ACT == 1) x = gelu_f(x);
                C[(size_t)m * N + n] = f2bf(x);
            }
        }
    }
}

// ---------------- V head-transpose: Vb[B*S][E] -> Vt[B*H][64 d][2048 s] ----------------
__global__ __launch_bounds__(256) void vtrans_kernel(
    const __hip_bfloat16* __restrict__ Vb, __hip_bfloat16* __restrict__ Vt)
{
    const int bh = blockIdx.y;               // b*8+h
    const int b = bh >> 3, h = bh & 7;
    const int s0 = blockIdx.x * 64;
    __shared__ alignas(16) __hip_bfloat16 L[64][72];
    const int t = threadIdx.x;
    for (int c = t; c < 512; c += 256) {
        int row = c >> 3, g = c & 7;
        *reinterpret_cast<uint4*>(&L[row][g * 8]) =
            *reinterpret_cast<const uint4*>(Vb + (size_t)(b * SS + s0 + row) * EMBED + h * 64 + g * 8);
    }
    __syncthreads();
    for (int c = t; c < 512; c += 256) {
        int d = c >> 3, g = c & 7;
        alignas(16) __hip_bfloat16 tmp[8];
        #pragma unroll
        for (int j = 0; j < 8; ++j) tmp[j] = L[g * 8 + j][d];
        *reinterpret_cast<uint4*>(Vt + ((size_t)bh * 64 + d) * SS + s0 + g * 8) =
            *reinterpret_cast<const uint4*>(tmp);
    }
}

// ---------------- MFMA flash attention, transposed softmax ----------------
// grid (S/64, B*H), block 256. Wave w owns 16 queries (q = q0 + w*16 + r).
// QK^T computed as S^T = K·Q^T so each lane holds all 16 scores of one query.
__global__ __launch_bounds__(256) void attn_mfma_kernel(
    const __hip_bfloat16* __restrict__ Qg,
    const __hip_bfloat16* __restrict__ Kg,
    const __hip_bfloat16* __restrict__ Vt,
    __hip_bfloat16* __restrict__ ctx)
{
    const int bh = blockIdx.y;
    const int b = bh >> 3, h = bh & 7;
    const int q0 = blockIdx.x * 64;
    const int t = threadIdx.x;
    const int w = t >> 6, lane = t & 63;
    const int quad = lane >> 4, r = lane & 15;

    __shared__ alignas(16) __hip_bfloat16 Ks[64][72];
    __shared__ alignas(16) __hip_bfloat16 VsT[64][72];   // [d][key]
    __shared__ alignas(16) __hip_bfloat16 Ps[4][16][72]; // [wave][q][key]

    const size_t bbase = (size_t)b * SS * EMBED;
    const size_t hoff = (size_t)h * HDIM;
    const size_t vtbase = (size_t)bh * HDIM * SS;

    // Q fragments, pre-scaled by 1/sqrt(Dh). Used as B-operand of S^T = K·Q^T:
    // B[k=quad*8+j][n=r] == Q[q=r][d=quad*8+j]  (same layout as the old A-frag)
    short8 aq[2];
    {
        const __hip_bfloat16* qrow = Qg + bbase + (size_t)(q0 + w * 16 + r) * EMBED + hoff;
        short8 t0 = *reinterpret_cast<const short8*>(qrow + quad * 8);
        short8 t1 = *reinterpret_cast<const short8*>(qrow + 32 + quad * 8);
        #pragma unroll
        for (int i = 0; i < 8; ++i) {
            ((__hip_bfloat16*)&aq[0])[i] = f2bf(bf2f(((const __hip_bfloat16*)&t0)[i]) * 0.125f);
            ((__hip_bfloat16*)&aq[1])[i] = f2bf(bf2f(((const __hip_bfloat16*)&t1)[i]) * 0.125f);
        }
    }

    float m_run = -1e30f;   // per-lane: running max of query q=r (replicated over quads)
    float l_run = 0.f;
    floatx4 o_acc[4];
    #pragma unroll
    for (int nt = 0; nt < 4; ++nt) o_acc[nt] = (floatx4){0.f, 0.f, 0.f, 0.f};

    for (int kt = 0; kt < SS; kt += 64) {
        __syncthreads();
        #pragma unroll
        for (int c = t; c < 512; c += 256) {
            int row = c >> 3, col = (c & 7) * 8;
            *reinterpret_cast<uint4*>(&Ks[row][col]) =
                *reinterpret_cast<const uint4*>(Kg + bbase + (size_t)(kt + row) * EMBED + hoff + col);
            *reinterpret_cast<uint4*>(&VsT[row][col]) =
                *reinterpret_cast<const uint4*>(Vt + vtbase + (size_t)row * SS + kt + col);
        }
        __syncthreads();

        // S^T tiles: sc[nt][reg] = score(q = r, k = nt*16 + quad*4 + reg)
        floatx4 sc[4];
        #pragma unroll
        for (int nt = 0; nt < 4; ++nt) sc[nt] = (floatx4){0.f, 0.f, 0.f, 0.f};
        #pragma unroll
        for (int nt = 0; nt < 4; ++nt) {
            short8 ak0 = *reinterpret_cast<const short8*>(&Ks[nt * 16 + r][quad * 8]);
            short8 ak1 = *reinterpret_cast<const short8*>(&Ks[nt * 16 + r][32 + quad * 8]);
            sc[nt] = __builtin_amdgcn_mfma_f32_16x16x32_bf16(ak0, aq[0], sc[nt], 0, 0, 0);
            sc[nt] = __builtin_amdgcn_mfma_f32_16x16x32_bf16(ak1, aq[1], sc[nt], 0, 0, 0);
        }

        // tile max over this lane's 16 scores, then across the 4 quads of same r
        float mt = fmaxf(fmaxf(fmaxf(sc[0][0], sc[0][1]), fmaxf(sc[0][2], sc[0][3])),
                         fmaxf(fmaxf(sc[1][0], sc[1][1]), fmaxf(sc[1][2], sc[1][3])));
        mt = fmaxf(mt, fmaxf(fmaxf(fmaxf(sc[2][0], sc[2][1]), fmaxf(sc[2][2], sc[2][3])),
                             fmaxf(fmaxf(sc[3][0], sc[3][1]), fmaxf(sc[3][2], sc[3][3]))));
        mt = fmaxf(mt, __shfl_xor(mt, 16, 64));
        mt = fmaxf(mt, __shfl_xor(mt, 32, 64));

        float mn = fmaxf(m_run, mt);
        float alpha = __expf(m_run - mn);
        m_run = mn;

        float ps = 0.f;
        #pragma unroll
        for (int nt = 0; nt < 4; ++nt) {
            float p0 = __expf(sc[nt][0] - mn), p1 = __expf(sc[nt][1] - mn);
            float p2 = __expf(sc[nt][2] - mn), p3 = __expf(sc[nt][3] - mn);
            ps += (p0 + p1) + (p2 + p3);
            alignas(8) __hip_bfloat16 pk[4] = {f2bf(p0), f2bf(p1), f2bf(p2), f2bf(p3)};
            // Ps[q=r][k = nt*16 + quad*4 + 0..3]
            *reinterpret_cast<uint2*>(&Ps[w][r][nt * 16 + quad * 4]) =
                *reinterpret_cast<const uint2*>(pk);
        }
        ps += __shfl_xor(ps, 16, 64);
        ps += __shfl_xor(ps, 32, 64);
        l_run = l_run * alpha + ps;

        // rescale O: o_acc row q' = quad*4+v; alpha(q') lives in lane q' (quad 0)
        #pragma unroll
        for (int v = 0; v < 4; ++v) {
            float av = __shfl(alpha, quad * 4 + v, 64);
            o_acc[0][v] *= av; o_acc[1][v] *= av;
            o_acc[2][v] *= av; o_acc[3][v] *= av;
        }

        // PV: A = P[q][k] from Ps, B = V^T (VsT rows)
        short8 ap0 = *reinterpret_cast<const short8*>(&Ps[w][r][quad * 8]);
        short8 ap1 = *reinterpret_cast<const short8*>(&Ps[w][r][32 + quad * 8]);
        #pragma unroll
        for (int nt = 0; nt < 4; ++nt) {
            short8 bv0 = *reinterpret_cast<const short8*>(&VsT[nt * 16 + r][quad * 8]);
            short8 bv1 = *reinterpret_cast<const short8*>(&VsT[nt * 16 + r][32 + quad * 8]);
            o_acc[nt] = __builtin_amdgcn_mfma_f32_16x16x32_bf16(ap0, bv0, o_acc[nt], 0, 0, 0);
            o_acc[nt] = __builtin_amdgcn_mfma_f32_16x16x32_bf16(ap1, bv1, o_acc[nt], 0, 0, 0);
        }
    }

    // epilogue: O[row=quad*4+v][col=nt*16+r] / l(row)
    #pragma unroll
    for (int v = 0; v < 4; ++v) {
        float lv = __shfl(l_run, quad * 4 + v, 64);
        float inv = 1.0f / lv;
        int q = q0 + w * 16 + quad * 4 + v;
        __hip_bfloat16* orow = ctx + bbase + (size_t)q * EMBED + hoff;
        #pragma unroll
        for (int nt = 0; nt < 4; ++nt)
            orow[nt * 16 + r] = f2bf(o_acc[nt][v] * inv);
    }
}

// ---------------- fused residual-add + LayerNorm ----------------
__device__ inline float block_reduce_sum(float v, float* sbuf) {
    #pragma unroll
    for (int off = 32; off; off >>= 1) v += __shfl_xor(v, off, 64);
    int wave = threadIdx.x >> 6;
    if ((threadIdx.x & 63) == 0) sbuf[wave] = v;
    __syncthreads();
    float r = sbuf[0] + sbuf[1] + sbuf[2] + sbuf[3];
    __syncthreads();
    return r;
}

__global__ __launch_bounds__(256) void add_ln_kernel(
    const void* __restrict__ X,
    const __hip_bfloat16* __restrict__ Y,
    const void* __restrict__ g,
    const void* __restrict__ bt,
    void* __restrict__ out,
    int x_ext, int out_ext, const int* __restrict__ dflag)
{
    __shared__ float sbuf[4];
    const int f32 = *dflag;
    const bool x32 = (x_ext != 0) && (f32 != 0);
    const bool o32 = (out_ext != 0) && (f32 != 0);
    const int row = blockIdx.x;
    const size_t base = (size_t)row * EMBED;
    const int t = threadIdx.x;

    float xa = x32 ? ((const float*)X)[base + t]
                   : bf2f(((const __hip_bfloat16*)X)[base + t]);
    float xb = x32 ? ((const float*)X)[base + t + 256]
                   : bf2f(((const __hip_bfloat16*)X)[base + t + 256]);
    float x0 = xa + bf2f(Y[base + t]);
    float x1 = xb + bf2f(Y[base + t + 256]);
    float s = block_reduce_sum(x0 + x1, sbuf);
    float mu = s * (1.0f / EMBED);
    float d0 = x0 - mu, d1 = x1 - mu;
    float vs = block_reduce_sum(d0 * d0 + d1 * d1, sbuf);
    float rstd = rsqrtf(vs * (1.0f / EMBED) + LN_EPS);

    float g0 = f32 ? ((const float*)g)[t]        : bf2f(((const __hip_bfloat16*)g)[t]);
    float g1v = f32 ? ((const float*)g)[t + 256] : bf2f(((const __hip_bfloat16*)g)[t + 256]);
    float b0 = f32 ? ((const float*)bt)[t]        : bf2f(((const __hip_bfloat16*)bt)[t]);
    float b1v = f32 ? ((const float*)bt)[t + 256] : bf2f(((const __hip_bfloat16*)bt)[t + 256]);

    float o0 = d0 * rstd * g0 + b0;
    float o1 = d1 * rstd * g1v + b1v;
    if (o32) {
        ((float*)out)[base + t] = o0;
        ((float*)out)[base + t + 256] = o1;
    } else {
        ((__hip_bfloat16*)out)[base + t] = f2bf(o0);
        ((__hip_bfloat16*)out)[base + t + 256] = f2bf(o1);
    }
}

// ---------------- launch ----------------
extern "C" void kernel_launch(void* const* d_in, const int* in_sizes, int n_in,
                              void* d_out, int out_size, void* d_ws, size_t ws_size,
                              hipStream_t stream)
{
    (void)in_sizes; (void)n_in; (void)out_size; (void)ws_size;

    const void* query = d_in[0];
    const void* keyi  = d_in[1];
    const void* vali  = d_in[2];
    const void* Wq = d_in[3];  const void* bq = d_in[4];
    const void* Wk = d_in[5];  const void* bk = d_in[6];
    const void* Wv = d_in[7];  const void* bv = d_in[8];
    const void* Wo = d_in[9];  const void* bo = d_in[10];
    const void* g1 = d_in[11]; const void* be1 = d_in[12];
    const void* g2 = d_in[13]; const void* be2 = d_in[14];
    const void* W1 = d_in[15]; const void* b1 = d_in[16];
    const void* W2 = d_in[17]; const void* b2 = d_in[18];

    // ---- workspace: 64B flag + 6MB weightsT + 6 x 8MB units = 54 MB ----
    int* dflag = (int*)d_ws;
    __hip_bfloat16* p = (__hip_bfloat16*)((char*)d_ws + 64);
    __hip_bfloat16* WqT = p;
    __hip_bfloat16* WkT = WqT + 512 * 512;
    __hip_bfloat16* WvT = WkT + 512 * 512;
    __hip_bfloat16* WoT = WvT + 512 * 512;
    __hip_bfloat16* W1T = WoT + 512 * 512;
    __hip_bfloat16* W2T = W1T + 512 * 2048;
    __hip_bfloat16* buf = W2T + 512 * 2048;
    const size_t NB = (size_t)MROWS * EMBED;     // 4M elems
    __hip_bfloat16* Qb   = buf;                  // unit0
    __hip_bfloat16* Kb   = buf + NB;             // unit1
    __hip_bfloat16* Vb   = buf + 2 * NB;         // unit2
    __hip_bfloat16* Vt   = buf + 3 * NB;         // unit3
    __hip_bfloat16* ctx  = buf + 4 * NB;         // unit4
    __hip_bfloat16* prj  = buf + 5 * NB;         // unit5
    __hip_bfloat16* x1   = ctx;                  // unit4 (ctx dead after Wo GEMM)
    __hip_bfloat16* hbf  = Qb;                   // units 0..3 (all dead by FFN1)
    __hip_bfloat16* prj2 = prj;                  // unit5 (prj dead after LN1)

    detect_kernel<<<1, 64, 0, stream>>>(query, dflag);

    // coalesced LDS-tiled weight transposes
    transpose_tile_kernel<<<dim3(8, 8), 256, 0, stream>>>(Wq, WqT, 512, 512, dflag);
    transpose_tile_kernel<<<dim3(8, 8), 256, 0, stream>>>(Wk, WkT, 512, 512, dflag);
    transpose_tile_kernel<<<dim3(8, 8), 256, 0, stream>>>(Wv, WvT, 512, 512, dflag);
    transpose_tile_kernel<<<dim3(8, 8), 256, 0, stream>>>(Wo, WoT, 512, 512, dflag);
    transpose_tile_kernel<<<dim3(8, 32), 256, 0, stream>>>(W1, W1T, 512, 2048, dflag);
    transpose_tile_kernel<<<dim3(32, 8), 256, 0, stream>>>(W2, W2T, 2048, 512, dflag);

    // QKV projections: 128x64 tiles -> 512 blocks
    gemm_qkv_kernel<<<dim3(MROWS / 128, EMBED / 64), 256, 0, stream>>>(query, WqT, bq, Qb, MROWS, EMBED, EMBED, dflag);
    gemm_qkv_kernel<<<dim3(MROWS / 128, EMBED / 64), 256, 0, stream>>>(keyi,  WkT, bk, Kb, MROWS, EMBED, EMBED, dflag);
    gemm_qkv_kernel<<<dim3(MROWS / 128, EMBED / 64), 256, 0, stream>>>(vali,  WvT, bv, Vb, MROWS, EMBED, EMBED, dflag);

    vtrans_kernel<<<dim3(SS / 64, BB * NHEAD), 256, 0, stream>>>(Vb, Vt);

    attn_mfma_kernel<<<dim3(SS / 64, BB * NHEAD), 256, 0, stream>>>(Qb, Kb, Vt, ctx);

    // output projection + LN1 (128x64 lds tiles)
    gemm_lds_n64_kernel<0><<<dim3(MROWS / 128, EMBED / 64), 256, 0, stream>>>(ctx, WoT, bo, prj, MROWS, EMBED, EMBED, dflag);
    add_ln_kernel<<<MROWS, 256, 0, stream>>>(query, prj, g1, be1, x1, 1, 0, dflag);

    // FFN
    gemm_bt_lds_kernel<1><<<dim3(MROWS / 128, FFN / 128), 256, 0, stream>>>(x1, W1T, b1, hbf, MROWS, FFN, EMBED, dflag);
    gemm_lds_n64_kernel<0><<<dim3(MROWS / 128, EMBED / 64), 256, 0, stream>>>(hbf, W2T, b2, prj2, MROWS, EMBED, FFN, dflag);
    add_ln_kernel<<<MROWS, 256, 0, stream>>>(x1, prj2, g2, be2, d_out, 0, 1, dflag);
}

// Round 7
// 384.143 us; speedup vs baseline: 4.3946x; 1.1755x over previous
//
#include <hip/hip_runtime.h>
#include <hip/hip_bf16.h>
#include <math.h>

// Problem constants
#define EMBED 512
#define NHEAD 8
#define HDIM 64
#define FFN 2048
#define BB 4
#define SS 2048
#define MROWS (BB*SS)   // 8192
#define NB ((size_t)MROWS * EMBED)   // 4M elems = 2^22
#define LN_EPS 1e-5f

typedef __attribute__((ext_vector_type(8))) short short8;
typedef __attribute__((ext_vector_type(4))) float floatx4;

__device__ inline float bf2f(__hip_bfloat16 x) { return __bfloat162float(x); }
__device__ inline __hip_bfloat16 f2bf(float x) { return __float2bfloat16(x); }

__device__ inline float gelu_f(float x) {
    return 0.5f * x * (1.0f + erff(x * 0.70710678118654752f));
}

// async 16B global->LDS; LDS base wave-uniform, lanes spread +16B each
__device__ inline void async_copy16(const void* g, void* l) {
    __builtin_amdgcn_global_load_lds(
        (const __attribute__((address_space(1))) void*)g,
        (__attribute__((address_space(3))) void*)l, 16, 0, 0);
}

// ---------------- runtime dtype detection ----------------
__global__ void detect_kernel(const void* __restrict__ q, int* __restrict__ flag) {
    const float* qf = (const float*)q;
    int lane = threadIdx.x;          // 64 threads
    float v = qf[lane * 1024 + 7];
    bool ok = (v == v) && (fabsf(v) > 0x1p-40f) && (fabsf(v) < 0x1p40f);
    unsigned long long m = __ballot(ok);
    if (lane == 0) *flag = (__popcll(m) >= 32) ? 1 : 0;
}

// ---------------- q/k/v -> bf16 (convert or copy), 8 elems/thread ----------------
__global__ __launch_bounds__(256) void cvt_qkv_kernel(
    const void* __restrict__ q, const void* __restrict__ k, const void* __restrict__ v,
    __hip_bfloat16* __restrict__ out, const int* __restrict__ dflag)
{
    const int f32 = *dflag;
    size_t pos = ((size_t)blockIdx.x * 256 + threadIdx.x) * 8;   // grid covers 3*NB elems
    int sel = (int)(pos >> 22);
    size_t off = pos & (NB - 1);
    const void* src = sel == 0 ? q : sel == 1 ? k : v;
    if (f32) {
        const float* s = (const float*)src + off;
        float4 f0 = *reinterpret_cast<const float4*>(s);
        float4 f1 = *reinterpret_cast<const float4*>(s + 4);
        alignas(16) __hip_bfloat16 h[8] = {
            f2bf(f0.x), f2bf(f0.y), f2bf(f0.z), f2bf(f0.w),
            f2bf(f1.x), f2bf(f1.y), f2bf(f1.z), f2bf(f1.w)};
        *reinterpret_cast<uint4*>(out + pos) = *reinterpret_cast<const uint4*>(h);
    } else {
        *reinterpret_cast<uint4*>(out + pos) =
            *reinterpret_cast<const uint4*>((const __hip_bfloat16*)src + off);
    }
}

// ---------------- LDS-tiled transpose: src[R][C] -> dst[C][R], 64x64 tiles ----------------
__global__ __launch_bounds__(256) void transpose_tile_kernel(
    const void* __restrict__ src, __hip_bfloat16* __restrict__ dst,
    int R, int C, const int* __restrict__ dflag)
{
    const int f32 = *dflag;
    const int r0 = blockIdx.x * 64, c0 = blockIdx.y * 64;
    __shared__ __hip_bfloat16 L[64][65];
    const int t = threadIdx.x;
    for (int c = t; c < 4096; c += 256) {
        int lr = c >> 6, lc = c & 63;
        __hip_bfloat16 v = f32 ? f2bf(((const float*)src)[(size_t)(r0 + lr) * C + c0 + lc])
                               : ((const __hip_bfloat16*)src)[(size_t)(r0 + lr) * C + c0 + lc];
        L[lr][lc] = v;
    }
    __syncthreads();
    for (int c = t; c < 4096; c += 256) {
        int lr = c >> 6, lc = c & 63;
        dst[(size_t)(c0 + lr) * R + r0 + lc] = L[lc][lr];
    }
}

// merged 512x512 transpose x4 (z selects weight)
__global__ __launch_bounds__(256) void transpose_tile4_kernel(
    const void* __restrict__ s0, const void* __restrict__ s1,
    const void* __restrict__ s2, const void* __restrict__ s3,
    __hip_bfloat16* __restrict__ dbase,   // 4 x 512*512 contiguous
    const int* __restrict__ dflag)
{
    const int f32 = *dflag;
    const int which = blockIdx.z;
    const void* src = which == 0 ? s0 : which == 1 ? s1 : which == 2 ? s2 : s3;
    __hip_bfloat16* dst = dbase + (size_t)which * 512 * 512;
    const int r0 = blockIdx.x * 64, c0 = blockIdx.y * 64;
    __shared__ __hip_bfloat16 L[64][65];
    const int t = threadIdx.x;
    for (int c = t; c < 4096; c += 256) {
        int lr = c >> 6, lc = c & 63;
        __hip_bfloat16 v = f32 ? f2bf(((const float*)src)[(size_t)(r0 + lr) * 512 + c0 + lc])
                               : ((const __hip_bfloat16*)src)[(size_t)(r0 + lr) * 512 + c0 + lc];
        L[lr][lc] = v;
    }
    __syncthreads();
    for (int c = t; c < 4096; c += 256) {
        int lr = c >> 6, lc = c & 63;
        dst[(size_t)(c0 + lr) * 512 + r0 + lc] = L[lc][lr];
    }
}

// ---------------- GEMM (async LDS staging, bf16): 128x128 tile, BK=32 (m97 pattern) ----------------
template<int ACT>
__global__ __launch_bounds__(256) void gemm_bt_lds_kernel(
    const __hip_bfloat16* __restrict__ A,
    const __hip_bfloat16* __restrict__ Bt,
    const void* __restrict__ bias,
    __hip_bfloat16* __restrict__ C,
    int M, int N, int K, const int* __restrict__ dflag)
{
    const int f32 = *dflag;
    const int bm = blockIdx.x * 128;
    const int bn = blockIdx.y * 128;
    const int t = threadIdx.x;
    const int wave = t >> 6, lane = t & 63;
    const int wm = (wave >> 1) * 64, wn = (wave & 1) * 64;
    const int quad = lane >> 4, r = lane & 15;

    __shared__ alignas(16) __hip_bfloat16 As[128 * 32];
    __shared__ alignas(16) __hip_bfloat16 Bs[128 * 32];

    floatx4 acc[4][4];
    #pragma unroll
    for (int i = 0; i < 4; ++i)
        #pragma unroll
        for (int j = 0; j < 4; ++j)
            acc[i][j] = (floatx4){0.f, 0.f, 0.f, 0.f};

    const int c0 = wave * 128;

    for (int kt = 0; kt < K; kt += 32) {
        #pragma unroll
        for (int it = 0; it < 2; ++it) {
            int c = c0 + it * 64 + lane;
            int row = c >> 2, col = (c & 3) * 8;
            async_copy16(A + (size_t)(bm + row) * K + kt + col,
                         As + (size_t)(c0 + it * 64) * 8);
            async_copy16(Bt + (size_t)(bn + row) * K + kt + col,
                         Bs + (size_t)(c0 + it * 64) * 8);
        }
        __syncthreads();
        short8 af[4], bfr[4];
        #pragma unroll
        for (int i = 0; i < 4; ++i)
            af[i] = *reinterpret_cast<const short8*>(&As[(wm + i * 16 + r) * 32 + quad * 8]);
        #pragma unroll
        for (int j = 0; j < 4; ++j)
            bfr[j] = *reinterpret_cast<const short8*>(&Bs[(wn + j * 16 + r) * 32 + quad * 8]);
        #pragma unroll
        for (int i = 0; i < 4; ++i)
            #pragma unroll
            for (int j = 0; j < 4; ++j)
                acc[i][j] = __builtin_amdgcn_mfma_f32_16x16x32_bf16(af[i], bfr[j], acc[i][j], 0, 0, 0);
        __syncthreads();
    }

    #pragma unroll
    for (int j = 0; j < 4; ++j) {
        const int n = bn + wn + j * 16 + r;
        const float bvv = f32 ? ((const float*)bias)[n]
                              : bf2f(((const __hip_bfloat16*)bias)[n]);
        #pragma unroll
        for (int i = 0; i < 4; ++i) {
            #pragma unroll
            for (int v = 0; v < 4; ++v) {
                int m = bm + wm + i * 16 + quad * 4 + v;
                float x = acc[i][j][v] + bvv;
                if (ACT == 1) x = gelu_f(x);
                C[(size_t)m * N + n] = f2bf(x);
            }
        }
    }
}

// ---------------- fused QKV GEMM: 3 GEMMs in one launch ----------------
// grid (192, 4): sel = blockIdx.x>>6 picks {query,key,value}; A/Bt/out are contiguous per-matrix.
__global__ __launch_bounds__(256) void gemm_qkv_fused_kernel(
    const __hip_bfloat16* __restrict__ Acat,   // qbf|kbf|vbf, 3*NB
    const __hip_bfloat16* __restrict__ Wcat,   // WqT|WkT|WvT, 3*512*512
    const void* __restrict__ bq, const void* __restrict__ bk, const void* __restrict__ bv,
    __hip_bfloat16* __restrict__ Ocat,         // Qb|Kb|Vb, 3*NB
    const int* __restrict__ dflag)
{
    const int f32 = *dflag;
    const int sel = blockIdx.x >> 6;
    const __hip_bfloat16* A = Acat + (size_t)sel * NB;
    const __hip_bfloat16* Bt = Wcat + (size_t)sel * 512 * 512;
    const void* bias = sel == 0 ? bq : sel == 1 ? bk : bv;
    __hip_bfloat16* C = Ocat + (size_t)sel * NB;

    const int bm = (blockIdx.x & 63) * 128;
    const int bn = blockIdx.y * 128;
    const int t = threadIdx.x;
    const int wave = t >> 6, lane = t & 63;
    const int wm = (wave >> 1) * 64, wn = (wave & 1) * 64;
    const int quad = lane >> 4, r = lane & 15;
    const int K = EMBED, N = EMBED;

    __shared__ alignas(16) __hip_bfloat16 As[128 * 32];
    __shared__ alignas(16) __hip_bfloat16 Bs[128 * 32];

    floatx4 acc[4][4];
    #pragma unroll
    for (int i = 0; i < 4; ++i)
        #pragma unroll
        for (int j = 0; j < 4; ++j)
            acc[i][j] = (floatx4){0.f, 0.f, 0.f, 0.f};

    const int c0 = wave * 128;

    for (int kt = 0; kt < K; kt += 32) {
        #pragma unroll
        for (int it = 0; it < 2; ++it) {
            int c = c0 + it * 64 + lane;
            int row = c >> 2, col = (c & 3) * 8;
            async_copy16(A + (size_t)(bm + row) * K + kt + col,
                         As + (size_t)(c0 + it * 64) * 8);
            async_copy16(Bt + (size_t)(bn + row) * K + kt + col,
                         Bs + (size_t)(c0 + it * 64) * 8);
        }
        __syncthreads();
        short8 af[4], bfr[4];
        #pragma unroll
        for (int i = 0; i < 4; ++i)
            af[i] = *reinterpret_cast<const short8*>(&As[(wm + i * 16 + r) * 32 + quad * 8]);
        #pragma unroll
        for (int j = 0; j < 4; ++j)
            bfr[j] = *reinterpret_cast<const short8*>(&Bs[(wn + j * 16 + r) * 32 + quad * 8]);
        #pragma unroll
        for (int i = 0; i < 4; ++i)
            #pragma unroll
            for (int j = 0; j < 4; ++j)
                acc[i][j] = __builtin_amdgcn_mfma_f32_16x16x32_bf16(af[i], bfr[j], acc[i][j], 0, 0, 0);
        __syncthreads();
    }

    #pragma unroll
    for (int j = 0; j < 4; ++j) {
        const int n = bn + wn + j * 16 + r;
        const float bvv = f32 ? ((const float*)bias)[n]
                              : bf2f(((const __hip_bfloat16*)bias)[n]);
        #pragma unroll
        for (int i = 0; i < 4; ++i) {
            #pragma unroll
            for (int v = 0; v < 4; ++v) {
                int m = bm + wm + i * 16 + quad * 4 + v;
                C[(size_t)m * N + n] = f2bf(acc[i][j][v] + bvv);
            }
        }
    }
}

// ---------------- V head-transpose: Vb[B*S][E] -> Vt[B*H][64 d][2048 s] ----------------
__global__ __launch_bounds__(256) void vtrans_kernel(
    const __hip_bfloat16* __restrict__ Vb, __hip_bfloat16* __restrict__ Vt)
{
    const int bh = blockIdx.y;
    const int b = bh >> 3, h = bh & 7;
    const int s0 = blockIdx.x * 64;
    __shared__ alignas(16) __hip_bfloat16 L[64][72];
    const int t = threadIdx.x;
    for (int c = t; c < 512; c += 256) {
        int row = c >> 3, g = c & 7;
        *reinterpret_cast<uint4*>(&L[row][g * 8]) =
            *reinterpret_cast<const uint4*>(Vb + (size_t)(b * SS + s0 + row) * EMBED + h * 64 + g * 8);
    }
    __syncthreads();
    for (int c = t; c < 512; c += 256) {
        int d = c >> 3, g = c & 7;
        alignas(16) __hip_bfloat16 tmp[8];
        #pragma unroll
        for (int j = 0; j < 8; ++j) tmp[j] = L[g * 8 + j][d];
        *reinterpret_cast<uint4*>(Vt + ((size_t)bh * 64 + d) * SS + s0 + g * 8) =
            *reinterpret_cast<const uint4*>(tmp);
    }
}

// ---------------- MFMA flash attention, transposed softmax, async K/V staging ----------------
// grid (S/64, B*H), block 256. Wave w owns 16 queries (q = q0 + w*16 + r).
// K/V tiles staged via global_load_lds into m97-layout 64x32 slabs (read==write layout).
__global__ __launch_bounds__(256) void attn_mfma_kernel(
    const __hip_bfloat16* __restrict__ Qg,
    const __hip_bfloat16* __restrict__ Kg,
    const __hip_bfloat16* __restrict__ Vt,
    __hip_bfloat16* __restrict__ ctx)
{
    const int bh = blockIdx.y;
    const int b = bh >> 3, h = bh & 7;
    const int q0 = blockIdx.x * 64;
    const int t = threadIdx.x;
    const int w = t >> 6, lane = t & 63;
    const int quad = lane >> 4, r = lane & 15;

    // slabs: [slab][row][32 cols], row stride 32 elems = 16 dwords -> 2-way (free)
    __shared__ alignas(16) __hip_bfloat16 Ks[2][64 * 32];
    __shared__ alignas(16) __hip_bfloat16 Vs[2][64 * 32];
    __shared__ alignas(16) __hip_bfloat16 Ps[4][16][72];

    const size_t bbase = (size_t)b * SS * EMBED;
    const size_t hoff = (size_t)h * HDIM;
    const size_t vtbase = (size_t)bh * HDIM * SS;

    // Q fragments pre-scaled by 1/8; B-operand of S^T = K.Q^T
    short8 aq[2];
    {
        const __hip_bfloat16* qrow = Qg + bbase + (size_t)(q0 + w * 16 + r) * EMBED + hoff;
        short8 t0 = *reinterpret_cast<const short8*>(qrow + quad * 8);
        short8 t1 = *reinterpret_cast<const short8*>(qrow + 32 + quad * 8);
        #pragma unroll
        for (int i = 0; i < 8; ++i) {
            ((__hip_bfloat16*)&aq[0])[i] = f2bf(bf2f(((const __hip_bfloat16*)&t0)[i]) * 0.125f);
            ((__hip_bfloat16*)&aq[1])[i] = f2bf(bf2f(((const __hip_bfloat16*)&t1)[i]) * 0.125f);
        }
    }

    const int tensor = w >> 1;      // 0 = K, 1 = V
    const int slab = w & 1;
    const int srow = lane >> 2;     // 0..15 within row-group
    const int scol = (lane & 3) * 8;

    float m_run = -1e30f;
    float l_run = 0.f;
    floatx4 o_acc[4];
    #pragma unroll
    for (int nt = 0; nt < 4; ++nt) o_acc[nt] = (floatx4){0.f, 0.f, 0.f, 0.f};

    for (int kt = 0; kt < SS; kt += 64) {
        __syncthreads();
        // async staging: wave -> (tensor, slab), 4 row-groups of 16 rows each
        if (tensor == 0) {
            #pragma unroll
            for (int g = 0; g < 4; ++g) {
                int row = g * 16 + srow;
                async_copy16(Kg + bbase + (size_t)(kt + row) * EMBED + hoff + slab * 32 + scol,
                             &Ks[slab][g * 512]);
            }
        } else {
            #pragma unroll
            for (int g = 0; g < 4; ++g) {
                int row = g * 16 + srow;    // d index
                async_copy16(Vt + vtbase + (size_t)row * SS + kt + slab * 32 + scol,
                             &Vs[slab][g * 512]);
            }
        }
        __syncthreads();   // drains vmcnt

        // S^T tiles: sc[nt][reg] = score(q = r, k = nt*16 + quad*4 + reg)
        floatx4 sc[4];
        #pragma unroll
        for (int nt = 0; nt < 4; ++nt) sc[nt] = (floatx4){0.f, 0.f, 0.f, 0.f};
        #pragma unroll
        for (int nt = 0; nt < 4; ++nt) {
            short8 ak0 = *reinterpret_cast<const short8*>(&Ks[0][(nt * 16 + r) * 32 + quad * 8]);
            short8 ak1 = *reinterpret_cast<const short8*>(&Ks[1][(nt * 16 + r) * 32 + quad * 8]);
            sc[nt] = __builtin_amdgcn_mfma_f32_16x16x32_bf16(ak0, aq[0], sc[nt], 0, 0, 0);
            sc[nt] = __builtin_amdgcn_mfma_f32_16x16x32_bf16(ak1, aq[1], sc[nt], 0, 0, 0);
        }

        float mt = fmaxf(fmaxf(fmaxf(sc[0][0], sc[0][1]), fmaxf(sc[0][2], sc[0][3])),
                         fmaxf(fmaxf(sc[1][0], sc[1][1]), fmaxf(sc[1][2], sc[1][3])));
        mt = fmaxf(mt, fmaxf(fmaxf(fmaxf(sc[2][0], sc[2][1]), fmaxf(sc[2][2], sc[2][3])),
                             fmaxf(fmaxf(sc[3][0], sc[3][1]), fmaxf(sc[3][2], sc[3][3]))));
        mt = fmaxf(mt, __shfl_xor(mt, 16, 64));
        mt = fmaxf(mt, __shfl_xor(mt, 32, 64));

        float mn = fmaxf(m_run, mt);
        float alpha = __expf(m_run - mn);
        m_run = mn;

        float ps = 0.f;
        #pragma unroll
        for (int nt = 0; nt < 4; ++nt) {
            float p0 = __expf(sc[nt][0] - mn), p1 = __expf(sc[nt][1] - mn);
            float p2 = __expf(sc[nt][2] - mn), p3 = __expf(sc[nt][3] - mn);
            ps += (p0 + p1) + (p2 + p3);
            alignas(8) __hip_bfloat16 pk[4] = {f2bf(p0), f2bf(p1), f2bf(p2), f2bf(p3)};
            *reinterpret_cast<uint2*>(&Ps[w][r][nt * 16 + quad * 4]) =
                *reinterpret_cast<const uint2*>(pk);
        }
        ps += __shfl_xor(ps, 16, 64);
        ps += __shfl_xor(ps, 32, 64);
        l_run = l_run * alpha + ps;

        #pragma unroll
        for (int v = 0; v < 4; ++v) {
            float av = __shfl(alpha, quad * 4 + v, 64);
            o_acc[0][v] *= av; o_acc[1][v] *= av;
            o_acc[2][v] *= av; o_acc[3][v] *= av;
        }

        // PV: A = P (LDS round-trip), B = V^T slabs
        short8 ap0 = *reinterpret_cast<const short8*>(&Ps[w][r][quad * 8]);
        short8 ap1 = *reinterpret_cast<const short8*>(&Ps[w][r][32 + quad * 8]);
        #pragma unroll
        for (int nt = 0; nt < 4; ++nt) {
            short8 bv0 = *reinterpret_cast<const short8*>(&Vs[0][(nt * 16 + r) * 32 + quad * 8]);
            short8 bv1 = *reinterpret_cast<const short8*>(&Vs[1][(nt * 16 + r) * 32 + quad * 8]);
            o_acc[nt] = __builtin_amdgcn_mfma_f32_16x16x32_bf16(ap0, bv0, o_acc[nt], 0, 0, 0);
            o_acc[nt] = __builtin_amdgcn_mfma_f32_16x16x32_bf16(ap1, bv1, o_acc[nt], 0, 0, 0);
        }
    }

    #pragma unroll
    for (int v = 0; v < 4; ++v) {
        float lv = __shfl(l_run, quad * 4 + v, 64);
        float inv = 1.0f / lv;
        int q = q0 + w * 16 + quad * 4 + v;
        __hip_bfloat16* orow = ctx + bbase + (size_t)q * EMBED + hoff;
        #pragma unroll
        for (int nt = 0; nt < 4; ++nt)
            orow[nt * 16 + r] = f2bf(o_acc[nt][v] * inv);
    }
}

// ---------------- fused residual-add + LayerNorm ----------------
__device__ inline float block_reduce_sum(float v, float* sbuf) {
    #pragma unroll
    for (int off = 32; off; off >>= 1) v += __shfl_xor(v, off, 64);
    int wave = threadIdx.x >> 6;
    if ((threadIdx.x & 63) == 0) sbuf[wave] = v;
    __syncthreads();
    float r = sbuf[0] + sbuf[1] + sbuf[2] + sbuf[3];
    __syncthreads();
    return r;
}

__global__ __launch_bounds__(256) void add_ln_kernel(
    const void* __restrict__ X,
    const __hip_bfloat16* __restrict__ Y,
    const void* __restrict__ g,
    const void* __restrict__ bt,
    void* __restrict__ out,
    int x_ext, int out_ext, const int* __restrict__ dflag)
{
    __shared__ float sbuf[4];
    const int f32 = *dflag;
    const bool x32 = (x_ext != 0) && (f32 != 0);
    const bool o32 = (out_ext != 0) && (f32 != 0);
    const int row = blockIdx.x;
    const size_t base = (size_t)row * EMBED;
    const int t = threadIdx.x;

    float xa = x32 ? ((const float*)X)[base + t]
                   : bf2f(((const __hip_bfloat16*)X)[base + t]);
    float xb = x32 ? ((const float*)X)[base + t + 256]
                   : bf2f(((const __hip_bfloat16*)X)[base + t + 256]);
    float x0 = xa + bf2f(Y[base + t]);
    float x1 = xb + bf2f(Y[base + t + 256]);
    float s = block_reduce_sum(x0 + x1, sbuf);
    float mu = s * (1.0f / EMBED);
    float d0 = x0 - mu, d1 = x1 - mu;
    float vs = block_reduce_sum(d0 * d0 + d1 * d1, sbuf);
    float rstd = rsqrtf(vs * (1.0f / EMBED) + LN_EPS);

    float g0 = f32 ? ((const float*)g)[t]        : bf2f(((const __hip_bfloat16*)g)[t]);
    float g1v = f32 ? ((const float*)g)[t + 256] : bf2f(((const __hip_bfloat16*)g)[t + 256]);
    float b0 = f32 ? ((const float*)bt)[t]        : bf2f(((const __hip_bfloat16*)bt)[t]);
    float b1v = f32 ? ((const float*)bt)[t + 256] : bf2f(((const __hip_bfloat16*)bt)[t + 256]);

    float o0 = d0 * rstd * g0 + b0;
    float o1 = d1 * rstd * g1v + b1v;
    if (o32) {
        ((float*)out)[base + t] = o0;
        ((float*)out)[base + t + 256] = o1;
    } else {
        ((__hip_bfloat16*)out)[base + t] = f2bf(o0);
        ((__hip_bfloat16*)out)[base + t + 256] = f2bf(o1);
    }
}

// ---------------- launch ----------------
extern "C" void kernel_launch(void* const* d_in, const int* in_sizes, int n_in,
                              void* d_out, int out_size, void* d_ws, size_t ws_size,
                              hipStream_t stream)
{
    (void)in_sizes; (void)n_in; (void)out_size; (void)ws_size;

    const void* query = d_in[0];
    const void* keyi  = d_in[1];
    const void* vali  = d_in[2];
    const void* Wq = d_in[3];  const void* bq = d_in[4];
    const void* Wk = d_in[5];  const void* bk = d_in[6];
    const void* Wv = d_in[7];  const void* bv = d_in[8];
    const void* Wo = d_in[9];  const void* bo = d_in[10];
    const void* g1 = d_in[11]; const void* be1 = d_in[12];
    const void* g2 = d_in[13]; const void* be2 = d_in[14];
    const void* W1 = d_in[15]; const void* b1 = d_in[16];
    const void* W2 = d_in[17]; const void* b2 = d_in[18];

    // ---- workspace: 64B flag + 6MB weightsT + 6 x 8MB units = 54 MB ----
    int* dflag = (int*)d_ws;
    __hip_bfloat16* p = (__hip_bfloat16*)((char*)d_ws + 64);
    __hip_bfloat16* WqT = p;                       // WqT|WkT|WvT contiguous (fused B)
    __hip_bfloat16* WoT = WqT + 3 * 512 * 512;
    __hip_bfloat16* W1T = WoT + 512 * 512;
    __hip_bfloat16* W2T = W1T + 512 * 2048;
    __hip_bfloat16* buf = W2T + 512 * 2048;
    __hip_bfloat16* qkvbf = buf;                   // units 0..2 (cvt out, contiguous)
    __hip_bfloat16* QKVo  = buf + 3 * NB;          // units 3..5: Qb|Kb|Vb contiguous
    __hip_bfloat16* Qb = QKVo;
    __hip_bfloat16* Kb = QKVo + NB;
    __hip_bfloat16* Vb = QKVo + 2 * NB;
    // aliases (disjoint lifetimes):
    __hip_bfloat16* Vt   = buf;                    // unit0 (qbf dead after QKV GEMM)
    __hip_bfloat16* ctx  = buf + NB;               // unit1 (kbf dead)
    __hip_bfloat16* prj  = buf + 2 * NB;           // unit2 (vbf dead)
    __hip_bfloat16* x1   = Qb;                     // unit3 (Qb dead after attn)
    __hip_bfloat16* hbf  = Kb;                     // units 4..5 (Kb,Vb dead)
    __hip_bfloat16* prj2 = ctx;                    // unit1 (ctx dead after Wo GEMM)

    detect_kernel<<<1, 64, 0, stream>>>(query, dflag);

    // q/k/v -> bf16 (3*NB elems, 8/thread)
    cvt_qkv_kernel<<<(3 * NB / 8) / 256, 256, 0, stream>>>(query, keyi, vali, qkvbf, dflag);

    // weight transposes (coalesced LDS-tiled)
    transpose_tile4_kernel<<<dim3(8, 8, 4), 256, 0, stream>>>(Wq, Wk, Wv, Wo, WqT, dflag);
    transpose_tile_kernel<<<dim3(8, 32), 256, 0, stream>>>(W1, W1T, 512, 2048, dflag);
    transpose_tile_kernel<<<dim3(32, 8), 256, 0, stream>>>(W2, W2T, 2048, 512, dflag);

    // fused QKV projection: 768 blocks (3 blocks/CU)
    gemm_qkv_fused_kernel<<<dim3(192, 4), 256, 0, stream>>>(qkvbf, WqT, bq, bk, bv, QKVo, dflag);

    vtrans_kernel<<<dim3(SS / 64, BB * NHEAD), 256, 0, stream>>>(Vb, Vt);

    attn_mfma_kernel<<<dim3(SS / 64, BB * NHEAD), 256, 0, stream>>>(Qb, Kb, Vt, ctx);

    // output projection + LN1
    gemm_bt_lds_kernel<0><<<dim3(MROWS / 128, EMBED / 128), 256, 0, stream>>>(ctx, WoT, bo, prj, MROWS, EMBED, EMBED, dflag);
    add_ln_kernel<<<MROWS, 256, 0, stream>>>(query, prj, g1, be1, x1, 1, 0, dflag);

    // FFN
    gemm_bt_lds_kernel<1><<<dim3(MROWS / 128, FFN / 128), 256, 0, stream>>>(x1, W1T, b1, hbf, MROWS, FFN, EMBED, dflag);
    gemm_bt_lds_kernel<0><<<dim3(MROWS / 128, EMBED / 128), 256, 0, stream>>>(hbf, W2T, b2, prj2, MROWS, EMBED, FFN, dflag);
    add_ln_kernel<<<MROWS, 256, 0, stream>>>(x1, prj2, g2, be2, d_out, 0, 1, dflag);
}